// Round 9
// baseline (90.206 us; speedup 1.0000x reference)
//
#include <hip/hip_runtime.h>
#include <stdint.h>
#include <math.h>

#define BNTH 256           // 4 waves
#define CAP 1024           // max candidates per class-task (M ~ 330 +- 18)
#define MAXK 50
#define THRESH_F 0.05f
#define NMS_T 0.3f
#define SEGW_MAX 32        // 64-row segments per image (N <= 2048; problem: 32)
#define FG_MAX 24          // max fg classes (problem: 20)
#define NIMG_MAX 32        // max 2*Bimg (problem: 16)

// Decode one (image b, row n, class c) box exactly like the reference.
// (Arithmetic identical to the absmax-0.0 version -- do not reorder.)
__device__ __forceinline__ void decode_box(
    const float* __restrict__ rois, const float* __restrict__ pred,
    float H, float W, float scale,
    int b, int n, int c, int N, int C, float out[4])
{
    const float* r = rois + ((size_t)b * N + n) * 5;
    float bx1 = r[1], by1 = r[2], bx2 = r[3], by2 = r[4];
    float w  = bx2 - bx1 + 1.0f;
    float h  = by2 - by1 + 1.0f;
    float cx = bx1 + 0.5f * w;
    float cy = by1 + 0.5f * h;
    const float* d = pred + ((size_t)b * N + n) * 4 * C + 4 * c;
    float dx = d[0] * 0.1f, dy = d[1] * 0.1f;
    float dw = d[2] * 0.2f, dh = d[3] * 0.2f;
    float pcx = dx * w + cx;
    float pcy = dy * h + cy;
    float pw  = expf(dw) * w;
    float ph  = expf(dh) * h;
    float X1 = fminf(fmaxf(pcx - 0.5f * pw, 0.0f), W - 1.0f);
    float Y1 = fminf(fmaxf(pcy - 0.5f * ph, 0.0f), H - 1.0f);
    float X2 = fminf(fmaxf(pcx + 0.5f * pw, 0.0f), W - 1.0f);
    float Y2 = fminf(fmaxf(pcy + 0.5f * ph, 0.0f), H - 1.0f);
    out[0] = X1 / scale;
    out[1] = Y1 / scale;
    out[2] = X2 / scale;
    out[3] = Y2 / scale;
}

// Register bitonic sort, descending, over SN elements laid out as
// index i = s*64 + lane (slot-major), on ONE wave.  Keys are u64
// (score<<32|~row) reinterpreted as POSITIVE doubles (exponent normal,
// never NaN), so f64 fmax/fmin ordering == u64 ordering.
template<int SN>
__device__ __forceinline__ void bitonic_desc(double* kd, int lane)
{
    constexpr int NS = SN / 64;
    #pragma unroll
    for (int k = 2; k <= SN; k <<= 1) {
        #pragma unroll
        for (int j = k >> 1; j >= 1; j >>= 1) {
            if (j >= 64) {
                const int js = j >> 6;
                #pragma unroll
                for (int s = 0; s < NS; ++s) {
                    if ((s & js) == 0) {
                        const int sp = s | js;
                        const bool d = (((s << 6) & k) == 0);  // compile-time
                        const double a = kd[s], bb = kd[sp];
                        kd[s]  = d ? fmax(a, bb) : fmin(a, bb);
                        kd[sp] = d ? fmin(a, bb) : fmax(a, bb);
                    }
                }
            } else {
                #pragma unroll
                for (int s = 0; s < NS; ++s) {
                    const double o = __shfl_xor(kd[s], j);
                    const bool lower = (lane & j) == 0;
                    const bool d = ((((s << 6) | lane) & k) == 0);
                    const bool takeMax = (d == lower);
                    const double mx = fmax(kd[s], o);
                    const double mn = fmin(kd[s], o);
                    kd[s] = takeMax ? mx : mn;
                }
            }
        }
    }
}

// ONE kernel: one 4-wave block per (stream, image, fg-class).
// Round-7-verified body: collect (ballot compaction) -> shfl prefix scan ->
// gather -> wave-0 register bitonic sort -> all-wave decode -> wave-0
// sorted-scan NMS (shfl keep chain).  Then the round-8-verified tail:
// monotonic-ticket gate, LAST block performs select (top-50 cap) + combine.
__global__ __launch_bounds__(BNTH, 1) void nms_kernel(
    const float* __restrict__ rois_A, const float* __restrict__ cls_A,
    const float* __restrict__ pred_A, const float* __restrict__ info_A,
    const float* __restrict__ rois_B, const float* __restrict__ cls_B,
    const float* __restrict__ pred_B, const float* __restrict__ info_B,
    int Bimg, int N, int C,
    float* __restrict__ kept_scores, int* __restrict__ kcounts,
    float* __restrict__ cls_box,
    unsigned long long* __restrict__ ticket, float* __restrict__ out)
{
    const int FG = C - 1;
    const int bx = blockIdx.x;
    const int st  = bx / (Bimg * FG);
    const int rem = bx % (Bimg * FG);
    const int b = rem / FG;
    const int j = rem % FG;
    const int c = j + 1;
    const int tid = threadIdx.x;
    const int w = tid >> 6;
    const int lane = tid & 63;
    const int SEGW = (N + 63) >> 6;

    const float* rois = st ? rois_B : rois_A;
    const float* cls  = st ? cls_B  : cls_A;
    const float* pred = st ? pred_B : pred_A;
    const float* info = st ? info_B : info_A;

    __shared__ uint64_t segKeys[SEGW_MAX][64];
    __shared__ int segCnt[SEGW_MAX];
    __shared__ int offL[SEGW_MAX + 1];
    __shared__ uint64_t keysL[CAP];
    __shared__ float4 boxL[CAP];
    __shared__ float  sarL[CAP];
    __shared__ float4 keptL[MAXK];
    __shared__ int amlastL;
    // select scratch (used only by the last block)
    __shared__ float swSc[4][FG_MAX];
    __shared__ int   swKc[4][FG_MAX];
    __shared__ int   swCnt[4][FG_MAX];
    __shared__ float bestSL[NIMG_MAX][FG_MAX];
    __shared__ float4 bestBL[NIMG_MAX][FG_MAX];

    // ---- Collect: per-wave segment ballot compaction (no atomics) ----
    // Wave w, round r owns segment seg = w + 4*r; row = seg*64 + lane.
    const int ROUNDS = (SEGW + 3) >> 2;
    for (int r = 0; r < ROUNDS; ++r) {
        const int seg = w + 4 * r;
        if (seg < SEGW) {
            const int n = seg * 64 + lane;
            float sc = 0.0f;
            if (n < N) sc = cls[((size_t)b * N + n) * C + c];
            const bool val = sc > THRESH_F;
            const uint64_t bal = __ballot(val);
            if (val) {
                const int slot = __popcll(bal & ((1ull << lane) - 1ull));
                segKeys[seg][slot] =
                    ((uint64_t)__float_as_uint(sc) << 32) |
                    (uint32_t)(~(uint32_t)n);
            }
            if (lane == 0) segCnt[seg] = __popcll(bal);
        }
    }
    __syncthreads();

    // ---- Segment counts -> exclusive offsets (wave-0 shfl scan) ----
    if (tid < 64) {
        int v = (lane < SEGW) ? segCnt[lane] : 0;
        #pragma unroll
        for (int d = 1; d < 64; d <<= 1) {
            const int o = __shfl_up(v, d);
            if (lane >= d) v += o;
        }
        if (lane < SEGW) offL[lane + 1] = v;
        if (lane == 0) offL[0] = 0;
    }
    __syncthreads();
    const int Mfull = offL[SEGW];
    const int M = Mfull < CAP ? Mfull : CAP;

    // ---- Gather segments -> contiguous keysL (binary search, all waves) ----
    for (int i = tid; i < CAP; i += BNTH) {
        uint64_t k = 0ull;
        if (i < M) {
            int lo = 0, hi = SEGW;
            while (hi - lo > 1) {
                const int mid = (lo + hi) >> 1;
                if (offL[mid] <= i) lo = mid; else hi = mid;
            }
            k = segKeys[lo][i - offL[lo]];
        }
        keysL[i] = k;
    }
    __syncthreads();

    // ---- Sort descending on wave 0 (registers; smallest sufficient net) ----
    if (tid < 64) {
        if (M > 1) {
            if (M <= 512) {
                double kd[8];
                #pragma unroll
                for (int s = 0; s < 8; ++s)
                    kd[s] = __longlong_as_double((long long)keysL[s * 64 + lane]);
                bitonic_desc<512>(kd, lane);
                #pragma unroll
                for (int s = 0; s < 8; ++s)
                    keysL[s * 64 + lane] = (uint64_t)__double_as_longlong(kd[s]);
            } else {
                double kd[16];
                #pragma unroll
                for (int s = 0; s < 16; ++s)
                    kd[s] = __longlong_as_double((long long)keysL[s * 64 + lane]);
                bitonic_desc<1024>(kd, lane);
                #pragma unroll
                for (int s = 0; s < 16; ++s)
                    keysL[s * 64 + lane] = (uint64_t)__double_as_longlong(kd[s]);
            }
        }
    }
    __syncthreads();

    // ---- Decode in SORTED order, all 4 waves (4x latency hiding) ----
    const float H = info[b * 3 + 0];
    const float W = info[b * 3 + 1];
    const float scale = info[b * 3 + 2];
    for (int i = tid; i < M; i += BNTH) {
        const uint64_t u = keysL[i];
        const int n = (int)(~(uint32_t)u);
        float o[4];
        decode_box(rois, pred, H, W, scale, b, n, c, N, C, o);
        boxL[i] = make_float4(o[0], o[1], o[2], o[3]);
        sarL[i] = (o[2] - o[0] + 1.0f) * (o[3] - o[1] + 1.0f);
    }
    __syncthreads();

    // ---- Scan NMS over sorted order on wave 0, 64 candidates per batch ----
    if (tid < 64) {
        float* ksc = kept_scores + (size_t)bx * MAXK;
        int kcount = 0;
        float4 cls_best = make_float4(0.f, 0.f, 0.f, 0.f);

        for (int s = 0; s * 64 < M && kcount < MAXK; ++s) {
            const int ii = s * 64 + lane;
            const bool valid = (ii < M);
            float cx1 = 0.f, cy1 = 0.f, cx2 = 0.f, cy2 = 0.f, car = 1.0f, csc = 0.f;
            if (valid) {
                const float4 cb4 = boxL[ii];
                cx1 = cb4.x; cy1 = cb4.y; cx2 = cb4.z; cy2 = cb4.w;
                car = sarL[ii];
                csc = __uint_as_float((uint32_t)(keysL[ii] >> 32));
            }
            // Pre-suppression vs already-kept boxes (uniform loop, pipelined).
            bool sup = !valid;
            for (int q = 0; q < kcount; ++q) {
                const float4 kb = keptL[q];
                const float kar = (kb.z - kb.x + 1.0f) * (kb.w - kb.y + 1.0f);
                const float ix1 = fmaxf(kb.x, cx1), iy1 = fmaxf(kb.y, cy1);
                const float ix2 = fminf(kb.z, cx2), iy2 = fminf(kb.w, cy2);
                const float iw = fmaxf(ix2 - ix1 + 1.0f, 0.0f);
                const float ih = fmaxf(iy2 - iy1 + 1.0f, 0.0f);
                const float inter = iw * ih;
                sup = sup || (inter / (kar + car - inter) > NMS_T);
            }
            uint64_t alive = ~__ballot(sup);
            // Intra-batch serial keep loop (sorted rank order == lane order).
            while (alive != 0ull && kcount < MAXK) {
                const int l = __builtin_ctzll(alive);      // highest-ranked alive
                const float kx1 = __shfl(cx1, l), ky1 = __shfl(cy1, l);
                const float kx2 = __shfl(cx2, l), ky2 = __shfl(cy2, l);
                const float kar = (kx2 - kx1 + 1.0f) * (ky2 - ky1 + 1.0f);
                if (lane == l) {
                    keptL[kcount] = make_float4(cx1, cy1, cx2, cy2);
                    ksc[kcount] = csc;
                }
                if (kcount == 0) cls_best = make_float4(kx1, ky1, kx2, ky2);
                const float ix1 = fmaxf(kx1, cx1), iy1 = fmaxf(ky1, cy1);
                const float ix2 = fminf(kx2, cx2), iy2 = fminf(ky2, cy2);
                const float iw = fmaxf(ix2 - ix1 + 1.0f, 0.0f);
                const float ih = fmaxf(iy2 - iy1 + 1.0f, 0.0f);
                const float inter = iw * ih;
                const bool s2 = (inter / (kar + car - inter) > NMS_T);
                alive &= ~__ballot(s2);
                alive &= ~(1ull << l);     // keeper always removed
                kcount++;
            }
        }

        if (lane == 0) {
            kcounts[bx] = kcount;
            float* cbp = cls_box + (size_t)bx * 4;
            cbp[0] = cls_best.x; cbp[1] = cls_best.y;
            cbp[2] = cls_best.z; cbp[3] = cls_best.w;
        }
    }
    __syncthreads();

    // ---- Monotonic-ticket gate: last finished block does select+combine ----
    __threadfence();
    if (tid == 0) {
        const unsigned long long t = atomicAdd(ticket, 1ull);
        amlastL = ((t % (unsigned long long)gridDim.x) ==
                   (unsigned long long)(gridDim.x - 1)) ? 1 : 0;
    }
    __syncthreads();
    if (!amlastL) return;
    __threadfence();   // acquire: all blocks' outputs now visible

    // ---- Select: wave w handles images w, w+4, ... (no barriers inside) ----
    const int nimg = 2 * Bimg;
    for (int img = w; img < nimg; img += 4) {
        int kc_l = 0; float sv_l = -INFINITY;
        if (lane < FG) {
            kc_l = kcounts[img * FG + lane];
            if (kc_l > 0) sv_l = kept_scores[((size_t)img * FG + lane) * MAXK];
            swKc[w][lane] = kc_l;
            swSc[w][lane] = sv_l;
            swCnt[w][lane] = 0;
        }
        // Count entries strictly greater than each class's best.
        // Kept lists are sorted desc -> break at first !greater.
        for (int p = lane; p < FG * FG; p += 64) {
            const int cc = p / FG, c2 = p % FG;
            const float sc = swSc[w][cc];
            const int k2 = swKc[w][c2];
            int cnt = 0;
            if (swKc[w][cc] > 0) {
                const float* kp = kept_scores + ((size_t)img * FG + c2) * MAXK;
                for (int k = 0; k < k2; ++k) {
                    const float v = kp[k];
                    const bool greater = (v > sc) || (v == sc && c2 < cc);
                    if (!greater) break;
                    cnt++;
                }
            }
            if (cnt) atomicAdd(&swCnt[w][cc], cnt);
        }
        // Global best detection (max score, ties -> lower class).
        uint32_t mu = 0u;
        if (lane < FG && kc_l > 0) {
            const uint32_t bb = __float_as_uint(sv_l);
            mu = (bb & 0x80000000u) ? ~bb : (bb | 0x80000000u);
        }
        uint64_t gkey = (mu == 0u) ? 0ull
                        : (((uint64_t)mu << 8) | (uint64_t)(255 - lane));
        #pragma unroll
        for (int m = 1; m < 64; m <<= 1) {
            const uint64_t o = __shfl_xor(gkey, m);
            if (o > gkey) gkey = o;
        }
        float4 gbox;
        if ((gkey >> 8) != 0ull) {
            const int g = 255 - (int)(gkey & 0xFFull);
            gbox = *(const float4*)(cls_box + ((size_t)img * FG + g) * 4);
        } else {
            const int st2 = img >= Bimg;
            const int b2  = img - st2 * Bimg;
            const float* rois2 = st2 ? rois_B : rois_A;
            const float* pred2 = st2 ? pred_B : pred_A;
            const float* info2 = st2 ? info_B : info_A;
            float o[4];
            decode_box(rois2, pred2, info2[b2 * 3], info2[b2 * 3 + 1],
                       info2[b2 * 3 + 2], b2, 0, 1, N, C, o);
            gbox = make_float4(o[0], o[1], o[2], o[3]);
        }
        if (lane < FG) {
            const int total = swCnt[w][lane];
            const bool in = (kc_l > 0 && total < MAXK);
            bestSL[img][lane] = in ? sv_l : -INFINITY;
            bestBL[img][lane] = in
                ? *(const float4*)(cls_box + ((size_t)img * FG + lane) * 4)
                : gbox;
        }
    }
    __syncthreads();

    // ---- Combine (wave 0): joint = sA*sB (IEEE -inf*-inf=+inf), argmax ----
    if (tid < Bimg) {
        const int i = tid;
        float bj = 0.0f;
        int cls_ = 0;
        for (int cc = 0; cc < FG; ++cc) {
            const float v = bestSL[i][cc] * bestSL[Bimg + i][cc];
            if (cc == 0 || v > bj) { bj = v; cls_ = cc; }
        }
        const float4 bA = bestBL[i][cls_];
        const float4 bB = bestBL[Bimg + i][cls_];
        out[i * 4 + 0] = bA.x; out[i * 4 + 1] = bA.y;
        out[i * 4 + 2] = bA.z; out[i * 4 + 3] = bA.w;
        out[Bimg * 4 + i * 4 + 0] = bB.x; out[Bimg * 4 + i * 4 + 1] = bB.y;
        out[Bimg * 4 + i * 4 + 2] = bB.z; out[Bimg * 4 + i * 4 + 3] = bB.w;
    }
}

extern "C" void kernel_launch(void* const* d_in, const int* in_sizes, int n_in,
                              void* d_out, int out_size, void* d_ws, size_t ws_size,
                              hipStream_t stream) {
    const float* rois_A = (const float*)d_in[0];
    const float* cls_A  = (const float*)d_in[1];
    const float* pred_A = (const float*)d_in[2];
    const float* info_A = (const float*)d_in[3];
    const float* rois_B = (const float*)d_in[4];
    const float* cls_B  = (const float*)d_in[5];
    const float* pred_B = (const float*)d_in[6];
    const float* info_B = (const float*)d_in[7];
    float* out = (float*)d_out;

    const int Bimg = in_sizes[3] / 3;                  // 8
    const int N    = in_sizes[0] / (Bimg * 5);         // 2000
    const int C    = in_sizes[1] / (Bimg * N);         // 21
    const int FG   = C - 1;                            // 20
    const int NSB  = 2 * Bimg * FG;                    // 320 tasks

    // Workspace: ticket (monotonic, never reset -- residues cycle exactly
    // once per call), then per-task outputs (fully rewritten every call).
    char* ws = (char*)d_ws;
    unsigned long long* ticket = (unsigned long long*)ws;
    size_t off = 256;
    float* kept_scores = (float*)(ws + off);               // [320][50]
    off += (size_t)NSB * MAXK * sizeof(float);
    int* kcounts = (int*)(ws + off);                       // [320]
    off += (size_t)NSB * sizeof(int);
    float* cls_box = (float*)(ws + off);                   // [320][4] (16B aligned)

    nms_kernel<<<NSB, BNTH, 0, stream>>>(
        rois_A, cls_A, pred_A, info_A,
        rois_B, cls_B, pred_B, info_B,
        Bimg, N, C, kept_scores, kcounts, cls_box, ticket, out);
}

// Round 10
// 83.037 us; speedup vs baseline: 1.0863x; 1.0863x over previous
//
#include <hip/hip_runtime.h>
#include <stdint.h>
#include <math.h>

#define BNTH 256           // 4 waves
#define CAP 1024           // max candidates per class-task (M ~ 330 +- 18)
#define MAXK 50
#define THRESH_F 0.05f
#define NMS_T 0.3f
#define SEGW_MAX 32        // 64-row segments per image (N <= 2048; problem: 32)
#define FG_MAX 24          // max fg classes (problem: 20)
#define NIMG_MAX 32        // max 2*Bimg (problem: 16)

// Decode one (image b, row n, class c) box exactly like the reference.
// (Arithmetic identical to the absmax-0.0 version -- do not reorder.)
__device__ __forceinline__ void decode_box(
    const float* __restrict__ rois, const float* __restrict__ pred,
    float H, float W, float scale,
    int b, int n, int c, int N, int C, float out[4])
{
    const float* r = rois + ((size_t)b * N + n) * 5;
    float bx1 = r[1], by1 = r[2], bx2 = r[3], by2 = r[4];
    float w  = bx2 - bx1 + 1.0f;
    float h  = by2 - by1 + 1.0f;
    float cx = bx1 + 0.5f * w;
    float cy = by1 + 0.5f * h;
    const float* d = pred + ((size_t)b * N + n) * 4 * C + 4 * c;
    float dx = d[0] * 0.1f, dy = d[1] * 0.1f;
    float dw = d[2] * 0.2f, dh = d[3] * 0.2f;
    float pcx = dx * w + cx;
    float pcy = dy * h + cy;
    float pw  = expf(dw) * w;
    float ph  = expf(dh) * h;
    float X1 = fminf(fmaxf(pcx - 0.5f * pw, 0.0f), W - 1.0f);
    float Y1 = fminf(fmaxf(pcy - 0.5f * ph, 0.0f), H - 1.0f);
    float X2 = fminf(fmaxf(pcx + 0.5f * pw, 0.0f), W - 1.0f);
    float Y2 = fminf(fmaxf(pcy + 0.5f * ph, 0.0f), H - 1.0f);
    out[0] = X1 / scale;
    out[1] = Y1 / scale;
    out[2] = X2 / scale;
    out[3] = Y2 / scale;
}

// Register bitonic sort, descending, over SN elements laid out as
// index i = s*64 + lane (slot-major), on ONE wave.  Keys are u64
// (score<<32|~row) reinterpreted as POSITIVE doubles (exponent normal,
// never NaN), so f64 fmax/fmin ordering == u64 ordering.
template<int SN>
__device__ __forceinline__ void bitonic_desc(double* kd, int lane)
{
    constexpr int NS = SN / 64;
    #pragma unroll
    for (int k = 2; k <= SN; k <<= 1) {
        #pragma unroll
        for (int j = k >> 1; j >= 1; j >>= 1) {
            if (j >= 64) {
                const int js = j >> 6;
                #pragma unroll
                for (int s = 0; s < NS; ++s) {
                    if ((s & js) == 0) {
                        const int sp = s | js;
                        const bool d = (((s << 6) & k) == 0);  // compile-time
                        const double a = kd[s], bb = kd[sp];
                        kd[s]  = d ? fmax(a, bb) : fmin(a, bb);
                        kd[sp] = d ? fmin(a, bb) : fmax(a, bb);
                    }
                }
            } else {
                #pragma unroll
                for (int s = 0; s < NS; ++s) {
                    const double o = __shfl_xor(kd[s], j);
                    const bool lower = (lane & j) == 0;
                    const bool d = ((((s << 6) | lane) & k) == 0);
                    const bool takeMax = (d == lower);
                    const double mx = fmax(kd[s], o);
                    const double mn = fmin(kd[s], o);
                    kd[s] = takeMax ? mx : mn;
                }
            }
        }
    }
}

// ONE kernel: one 4-wave block per (stream, image, fg-class).
// Round-7-verified body: collect -> scan -> gather -> wave-0 bitonic sort ->
// all-wave decode -> wave-0 sorted-scan NMS.  Tail: monotonic-ticket gate,
// LAST block performs select (LDS-staged, binary-search count) + combine.
__global__ __launch_bounds__(BNTH, 1) void nms_kernel(
    const float* __restrict__ rois_A, const float* __restrict__ cls_A,
    const float* __restrict__ pred_A, const float* __restrict__ info_A,
    const float* __restrict__ rois_B, const float* __restrict__ cls_B,
    const float* __restrict__ pred_B, const float* __restrict__ info_B,
    int Bimg, int N, int C,
    float* __restrict__ kept_scores, int* __restrict__ kcounts,
    float* __restrict__ cls_box,
    unsigned long long* __restrict__ ticket, float* __restrict__ out)
{
    const int FG = C - 1;
    const int bx = blockIdx.x;
    const int st  = bx / (Bimg * FG);
    const int rem = bx % (Bimg * FG);
    const int b = rem / FG;
    const int j = rem % FG;
    const int c = j + 1;
    const int tid = threadIdx.x;
    const int w = tid >> 6;
    const int lane = tid & 63;
    const int SEGW = (N + 63) >> 6;

    const float* rois = st ? rois_B : rois_A;
    const float* cls  = st ? cls_B  : cls_A;
    const float* pred = st ? pred_B : pred_A;
    const float* info = st ? info_B : info_A;

    __shared__ uint64_t segKeys[SEGW_MAX][64];
    __shared__ int segCnt[SEGW_MAX];
    __shared__ int offL[SEGW_MAX + 1];
    __shared__ uint64_t keysL[CAP];
    __shared__ float4 boxL[CAP];        // reused by tail as score staging
    __shared__ float  sarL[CAP];
    __shared__ float4 keptL[MAXK];
    __shared__ int amlastL;
    // select scratch (used only by the last block)
    __shared__ float swSc[4][FG_MAX];
    __shared__ int   swKc[4][FG_MAX];
    __shared__ int   swCnt[4][FG_MAX];
    __shared__ float bestSL[NIMG_MAX][FG_MAX];
    __shared__ float4 bestBL[NIMG_MAX][FG_MAX];

    // ---- Collect: per-wave segment ballot compaction (no atomics) ----
    const int ROUNDS = (SEGW + 3) >> 2;
    for (int r = 0; r < ROUNDS; ++r) {
        const int seg = w + 4 * r;
        if (seg < SEGW) {
            const int n = seg * 64 + lane;
            float sc = 0.0f;
            if (n < N) sc = cls[((size_t)b * N + n) * C + c];
            const bool val = sc > THRESH_F;
            const uint64_t bal = __ballot(val);
            if (val) {
                const int slot = __popcll(bal & ((1ull << lane) - 1ull));
                segKeys[seg][slot] =
                    ((uint64_t)__float_as_uint(sc) << 32) |
                    (uint32_t)(~(uint32_t)n);
            }
            if (lane == 0) segCnt[seg] = __popcll(bal);
        }
    }
    __syncthreads();

    // ---- Segment counts -> exclusive offsets (wave-0 shfl scan) ----
    if (tid < 64) {
        int v = (lane < SEGW) ? segCnt[lane] : 0;
        #pragma unroll
        for (int d = 1; d < 64; d <<= 1) {
            const int o = __shfl_up(v, d);
            if (lane >= d) v += o;
        }
        if (lane < SEGW) offL[lane + 1] = v;
        if (lane == 0) offL[0] = 0;
    }
    __syncthreads();
    const int Mfull = offL[SEGW];
    const int M = Mfull < CAP ? Mfull : CAP;

    // ---- Gather segments -> contiguous keysL (binary search, all waves) ----
    for (int i = tid; i < CAP; i += BNTH) {
        uint64_t k = 0ull;
        if (i < M) {
            int lo = 0, hi = SEGW;
            while (hi - lo > 1) {
                const int mid = (lo + hi) >> 1;
                if (offL[mid] <= i) lo = mid; else hi = mid;
            }
            k = segKeys[lo][i - offL[lo]];
        }
        keysL[i] = k;
    }
    __syncthreads();

    // ---- Sort descending on wave 0 (registers; smallest sufficient net) ----
    if (tid < 64) {
        if (M > 1) {
            if (M <= 512) {
                double kd[8];
                #pragma unroll
                for (int s = 0; s < 8; ++s)
                    kd[s] = __longlong_as_double((long long)keysL[s * 64 + lane]);
                bitonic_desc<512>(kd, lane);
                #pragma unroll
                for (int s = 0; s < 8; ++s)
                    keysL[s * 64 + lane] = (uint64_t)__double_as_longlong(kd[s]);
            } else {
                double kd[16];
                #pragma unroll
                for (int s = 0; s < 16; ++s)
                    kd[s] = __longlong_as_double((long long)keysL[s * 64 + lane]);
                bitonic_desc<1024>(kd, lane);
                #pragma unroll
                for (int s = 0; s < 16; ++s)
                    keysL[s * 64 + lane] = (uint64_t)__double_as_longlong(kd[s]);
            }
        }
    }
    __syncthreads();

    // ---- Decode in SORTED order, all 4 waves (4x latency hiding) ----
    const float H = info[b * 3 + 0];
    const float W = info[b * 3 + 1];
    const float scale = info[b * 3 + 2];
    for (int i = tid; i < M; i += BNTH) {
        const uint64_t u = keysL[i];
        const int n = (int)(~(uint32_t)u);
        float o[4];
        decode_box(rois, pred, H, W, scale, b, n, c, N, C, o);
        boxL[i] = make_float4(o[0], o[1], o[2], o[3]);
        sarL[i] = (o[2] - o[0] + 1.0f) * (o[3] - o[1] + 1.0f);
    }
    __syncthreads();

    // ---- Scan NMS over sorted order on wave 0, 64 candidates per batch ----
    if (tid < 64) {
        float* ksc = kept_scores + (size_t)bx * MAXK;
        int kcount = 0;
        float4 cls_best = make_float4(0.f, 0.f, 0.f, 0.f);

        for (int s = 0; s * 64 < M && kcount < MAXK; ++s) {
            const int ii = s * 64 + lane;
            const bool valid = (ii < M);
            float cx1 = 0.f, cy1 = 0.f, cx2 = 0.f, cy2 = 0.f, car = 1.0f, csc = 0.f;
            if (valid) {
                const float4 cb4 = boxL[ii];
                cx1 = cb4.x; cy1 = cb4.y; cx2 = cb4.z; cy2 = cb4.w;
                car = sarL[ii];
                csc = __uint_as_float((uint32_t)(keysL[ii] >> 32));
            }
            // Pre-suppression vs already-kept boxes (uniform loop, pipelined).
            bool sup = !valid;
            for (int q = 0; q < kcount; ++q) {
                const float4 kb = keptL[q];
                const float kar = (kb.z - kb.x + 1.0f) * (kb.w - kb.y + 1.0f);
                const float ix1 = fmaxf(kb.x, cx1), iy1 = fmaxf(kb.y, cy1);
                const float ix2 = fminf(kb.z, cx2), iy2 = fminf(kb.w, cy2);
                const float iw = fmaxf(ix2 - ix1 + 1.0f, 0.0f);
                const float ih = fmaxf(iy2 - iy1 + 1.0f, 0.0f);
                const float inter = iw * ih;
                sup = sup || (inter / (kar + car - inter) > NMS_T);
            }
            uint64_t alive = ~__ballot(sup);
            // Intra-batch serial keep loop (sorted rank order == lane order).
            while (alive != 0ull && kcount < MAXK) {
                const int l = __builtin_ctzll(alive);      // highest-ranked alive
                const float kx1 = __shfl(cx1, l), ky1 = __shfl(cy1, l);
                const float kx2 = __shfl(cx2, l), ky2 = __shfl(cy2, l);
                const float kar = (kx2 - kx1 + 1.0f) * (ky2 - ky1 + 1.0f);
                if (lane == l) {
                    keptL[kcount] = make_float4(cx1, cy1, cx2, cy2);
                    ksc[kcount] = csc;
                }
                if (kcount == 0) cls_best = make_float4(kx1, ky1, kx2, ky2);
                const float ix1 = fmaxf(kx1, cx1), iy1 = fmaxf(ky1, cy1);
                const float ix2 = fminf(kx2, cx2), iy2 = fminf(ky2, cy2);
                const float iw = fmaxf(ix2 - ix1 + 1.0f, 0.0f);
                const float ih = fmaxf(iy2 - iy1 + 1.0f, 0.0f);
                const float inter = iw * ih;
                const bool s2 = (inter / (kar + car - inter) > NMS_T);
                alive &= ~__ballot(s2);
                alive &= ~(1ull << l);     // keeper always removed
                kcount++;
            }
        }

        if (lane == 0) {
            kcounts[bx] = kcount;
            float* cbp = cls_box + (size_t)bx * 4;
            cbp[0] = cls_best.x; cbp[1] = cls_best.y;
            cbp[2] = cls_best.z; cbp[3] = cls_best.w;
        }
    }
    __syncthreads();

    // ---- Monotonic-ticket gate: last finished block does select+combine ----
    __threadfence();
    if (tid == 0) {
        const unsigned long long t = atomicAdd(ticket, 1ull);
        amlastL = ((t % (unsigned long long)gridDim.x) ==
                   (unsigned long long)(gridDim.x - 1)) ? 1 : 0;
    }
    __syncthreads();
    if (!amlastL) return;
    __threadfence();   // acquire: all blocks' outputs now visible

    // ---- Select: wave w handles images w, w+4, ...  Per image: stage the
    // 20x50 kept-score block into LDS (coalesced, pipelined), then count via
    // 6-step binary search per (cc,c2) pair (lists sorted desc -> prefix
    // predicate -> lower bound == exact count).  No barriers (wave-local).
    float* stageF = (float*)boxL;    // reuse: 16 KB >= 4 waves * FG*MAXK floats
    float* stg = stageF + w * FG * MAXK;
    const int nimg = 2 * Bimg;
    for (int img = w; img < nimg; img += 4) {
        const float* src = kept_scores + (size_t)img * FG * MAXK;
        for (int e = lane; e < FG * MAXK; e += 64) stg[e] = src[e];
        int kc_l = 0; float sv_l = -INFINITY;
        if (lane < FG) {
            kc_l = kcounts[img * FG + lane];
            if (kc_l > 0) sv_l = stg[lane * MAXK];
            swKc[w][lane] = kc_l;
            swSc[w][lane] = sv_l;
            swCnt[w][lane] = 0;
        }
        for (int p = lane; p < FG * FG; p += 64) {
            const int cc = p / FG, c2 = p % FG;
            const float sc = swSc[w][cc];
            const int k2 = swKc[w][c2];
            int cnt = 0;
            if (swKc[w][cc] > 0 && k2 > 0) {
                const float* lp = stg + c2 * MAXK;
                int lo = 0, hi = k2;
                while (lo < hi) {
                    const int mid = (lo + hi) >> 1;
                    const float v = lp[mid];
                    const bool greater = (v > sc) || (v == sc && c2 < cc);
                    if (greater) lo = mid + 1; else hi = mid;
                }
                cnt = lo;
            }
            if (cnt) atomicAdd(&swCnt[w][cc], cnt);
        }
        // Global best detection (max score, ties -> lower class).
        uint32_t mu = 0u;
        if (lane < FG && kc_l > 0) {
            const uint32_t bb = __float_as_uint(sv_l);
            mu = (bb & 0x80000000u) ? ~bb : (bb | 0x80000000u);
        }
        uint64_t gkey = (mu == 0u) ? 0ull
                        : (((uint64_t)mu << 8) | (uint64_t)(255 - lane));
        #pragma unroll
        for (int m = 1; m < 64; m <<= 1) {
            const uint64_t o = __shfl_xor(gkey, m);
            if (o > gkey) gkey = o;
        }
        float4 gbox;
        if ((gkey >> 8) != 0ull) {
            const int g = 255 - (int)(gkey & 0xFFull);
            gbox = *(const float4*)(cls_box + ((size_t)img * FG + g) * 4);
        } else {
            const int st2 = img >= Bimg;
            const int b2  = img - st2 * Bimg;
            const float* rois2 = st2 ? rois_B : rois_A;
            const float* pred2 = st2 ? pred_B : pred_A;
            const float* info2 = st2 ? info_B : info_A;
            float o[4];
            decode_box(rois2, pred2, info2[b2 * 3], info2[b2 * 3 + 1],
                       info2[b2 * 3 + 2], b2, 0, 1, N, C, o);
            gbox = make_float4(o[0], o[1], o[2], o[3]);
        }
        if (lane < FG) {
            const int total = swCnt[w][lane];
            const bool in = (kc_l > 0 && total < MAXK);
            bestSL[img][lane] = in ? sv_l : -INFINITY;
            bestBL[img][lane] = in
                ? *(const float4*)(cls_box + ((size_t)img * FG + lane) * 4)
                : gbox;
        }
    }
    __syncthreads();

    // ---- Combine (wave 0): joint = sA*sB (IEEE -inf*-inf=+inf), argmax ----
    if (tid < Bimg) {
        const int i = tid;
        float bj = 0.0f;
        int cls_ = 0;
        for (int cc = 0; cc < FG; ++cc) {
            const float v = bestSL[i][cc] * bestSL[Bimg + i][cc];
            if (cc == 0 || v > bj) { bj = v; cls_ = cc; }
        }
        const float4 bA = bestBL[i][cls_];
        const float4 bB = bestBL[Bimg + i][cls_];
        out[i * 4 + 0] = bA.x; out[i * 4 + 1] = bA.y;
        out[i * 4 + 2] = bA.z; out[i * 4 + 3] = bA.w;
        out[Bimg * 4 + i * 4 + 0] = bB.x; out[Bimg * 4 + i * 4 + 1] = bB.y;
        out[Bimg * 4 + i * 4 + 2] = bB.z; out[Bimg * 4 + i * 4 + 3] = bB.w;
    }
}

extern "C" void kernel_launch(void* const* d_in, const int* in_sizes, int n_in,
                              void* d_out, int out_size, void* d_ws, size_t ws_size,
                              hipStream_t stream) {
    const float* rois_A = (const float*)d_in[0];
    const float* cls_A  = (const float*)d_in[1];
    const float* pred_A = (const float*)d_in[2];
    const float* info_A = (const float*)d_in[3];
    const float* rois_B = (const float*)d_in[4];
    const float* cls_B  = (const float*)d_in[5];
    const float* pred_B = (const float*)d_in[6];
    const float* info_B = (const float*)d_in[7];
    float* out = (float*)d_out;

    const int Bimg = in_sizes[3] / 3;                  // 8
    const int N    = in_sizes[0] / (Bimg * 5);         // 2000
    const int C    = in_sizes[1] / (Bimg * N);         // 21
    const int FG   = C - 1;                            // 20
    const int NSB  = 2 * Bimg * FG;                    // 320 tasks

    // Workspace: ticket (monotonic, never reset -- residues cycle exactly
    // once per call), then per-task outputs (fully rewritten every call).
    char* ws = (char*)d_ws;
    unsigned long long* ticket = (unsigned long long*)ws;
    size_t off = 256;
    float* kept_scores = (float*)(ws + off);               // [320][50]
    off += (size_t)NSB * MAXK * sizeof(float);
    int* kcounts = (int*)(ws + off);                       // [320]
    off += (size_t)NSB * sizeof(int);
    float* cls_box = (float*)(ws + off);                   // [320][4] (16B aligned)

    nms_kernel<<<NSB, BNTH, 0, stream>>>(
        rois_A, cls_A, pred_A, info_A,
        rois_B, cls_B, pred_B, info_B,
        Bimg, N, C, kept_scores, kcounts, cls_box, ticket, out);
}

// Round 11
// 63.562 us; speedup vs baseline: 1.4192x; 1.3064x over previous
//
#include <hip/hip_runtime.h>
#include <stdint.h>
#include <math.h>

#define BNTH 256           // 4 waves
#define CAP 1024           // max candidates per class-task (M ~ 330 +- 18)
#define MAXK 50
#define THRESH_F 0.05f
#define NMS_T 0.3f
#define SEGW_MAX 32        // 64-row segments per image (N <= 2048; problem: 32)
#define FG_MAX 24          // max fg classes (problem: 20)
#define NIMG_MAX 32        // max 2*Bimg (problem: 16)

// Decode one (image b, row n, class c) box exactly like the reference.
// (Arithmetic identical to the absmax-0.0 version -- do not reorder.)
__device__ __forceinline__ void decode_box(
    const float* __restrict__ rois, const float* __restrict__ pred,
    float H, float W, float scale,
    int b, int n, int c, int N, int C, float out[4])
{
    const float* r = rois + ((size_t)b * N + n) * 5;
    float bx1 = r[1], by1 = r[2], bx2 = r[3], by2 = r[4];
    float w  = bx2 - bx1 + 1.0f;
    float h  = by2 - by1 + 1.0f;
    float cx = bx1 + 0.5f * w;
    float cy = by1 + 0.5f * h;
    const float* d = pred + ((size_t)b * N + n) * 4 * C + 4 * c;
    float dx = d[0] * 0.1f, dy = d[1] * 0.1f;
    float dw = d[2] * 0.2f, dh = d[3] * 0.2f;
    float pcx = dx * w + cx;
    float pcy = dy * h + cy;
    float pw  = expf(dw) * w;
    float ph  = expf(dh) * h;
    float X1 = fminf(fmaxf(pcx - 0.5f * pw, 0.0f), W - 1.0f);
    float Y1 = fminf(fmaxf(pcy - 0.5f * ph, 0.0f), H - 1.0f);
    float X2 = fminf(fmaxf(pcx + 0.5f * pw, 0.0f), W - 1.0f);
    float Y2 = fminf(fmaxf(pcy + 0.5f * ph, 0.0f), H - 1.0f);
    out[0] = X1 / scale;
    out[1] = Y1 / scale;
    out[2] = X2 / scale;
    out[3] = Y2 / scale;
}

// Register bitonic sort, descending, over SN elements laid out as
// index i = s*64 + lane (slot-major), on ONE wave.  Keys are u64
// (score<<32|~row) reinterpreted as POSITIVE doubles (exponent normal,
// never NaN), so f64 fmax/fmin ordering == u64 ordering.
template<int SN>
__device__ __forceinline__ void bitonic_desc(double* kd, int lane)
{
    constexpr int NS = SN / 64;
    #pragma unroll
    for (int k = 2; k <= SN; k <<= 1) {
        #pragma unroll
        for (int j = k >> 1; j >= 1; j >>= 1) {
            if (j >= 64) {
                const int js = j >> 6;
                #pragma unroll
                for (int s = 0; s < NS; ++s) {
                    if ((s & js) == 0) {
                        const int sp = s | js;
                        const bool d = (((s << 6) & k) == 0);  // compile-time
                        const double a = kd[s], bb = kd[sp];
                        kd[s]  = d ? fmax(a, bb) : fmin(a, bb);
                        kd[sp] = d ? fmin(a, bb) : fmax(a, bb);
                    }
                }
            } else {
                #pragma unroll
                for (int s = 0; s < NS; ++s) {
                    const double o = __shfl_xor(kd[s], j);
                    const bool lower = (lane & j) == 0;
                    const bool d = ((((s << 6) | lane) & k) == 0);
                    const bool takeMax = (d == lower);
                    const double mx = fmax(kd[s], o);
                    const double mn = fmin(kd[s], o);
                    kd[s] = takeMax ? mx : mn;
                }
            }
        }
    }
}

// ONE kernel: one 4-wave block per (stream, image, fg-class).
// Round-7-verified body.  Tail v2 (distributed): per-image done counter --
// the 20th class-block of each image performs that image's select with all
// 256 threads (overlapped with other blocks' bodies); a global counter gates
// the final tiny combine in the very last select block.
__global__ __launch_bounds__(BNTH, 1) void nms_kernel(
    const float* __restrict__ rois_A, const float* __restrict__ cls_A,
    const float* __restrict__ pred_A, const float* __restrict__ info_A,
    const float* __restrict__ rois_B, const float* __restrict__ cls_B,
    const float* __restrict__ pred_B, const float* __restrict__ info_B,
    int Bimg, int N, int C,
    float* __restrict__ kept_scores, int* __restrict__ kcounts,
    float* __restrict__ cls_box,
    unsigned long long* __restrict__ done_img,
    unsigned long long* __restrict__ done_all,
    float* __restrict__ best_s, float* __restrict__ best_b,
    float* __restrict__ out)
{
    const int FG = C - 1;
    const int bx = blockIdx.x;
    const int st  = bx / (Bimg * FG);
    const int rem = bx % (Bimg * FG);
    const int b = rem / FG;
    const int j = rem % FG;
    const int c = j + 1;
    const int tid = threadIdx.x;
    const int w = tid >> 6;
    const int lane = tid & 63;
    const int SEGW = (N + 63) >> 6;
    const int img = st * Bimg + b;
    const int nimg = 2 * Bimg;

    const float* rois = st ? rois_B : rois_A;
    const float* cls  = st ? cls_B  : cls_A;
    const float* pred = st ? pred_B : pred_A;
    const float* info = st ? info_B : info_A;

    __shared__ uint64_t segKeys[SEGW_MAX][64];
    __shared__ int segCnt[SEGW_MAX];
    __shared__ int offL[SEGW_MAX + 1];
    __shared__ uint64_t keysL[CAP];
    __shared__ float4 boxL[CAP];        // reused by tail as score staging
    __shared__ float  sarL[CAP];
    __shared__ float4 keptL[MAXK];
    __shared__ int selL, combL;
    __shared__ float selSc[FG_MAX];
    __shared__ int   selKc[FG_MAX];
    __shared__ int   selCnt[FG_MAX];

    // ---- Collect: per-wave segment ballot compaction (no atomics) ----
    const int ROUNDS = (SEGW + 3) >> 2;
    for (int r = 0; r < ROUNDS; ++r) {
        const int seg = w + 4 * r;
        if (seg < SEGW) {
            const int n = seg * 64 + lane;
            float sc = 0.0f;
            if (n < N) sc = cls[((size_t)b * N + n) * C + c];
            const bool val = sc > THRESH_F;
            const uint64_t bal = __ballot(val);
            if (val) {
                const int slot = __popcll(bal & ((1ull << lane) - 1ull));
                segKeys[seg][slot] =
                    ((uint64_t)__float_as_uint(sc) << 32) |
                    (uint32_t)(~(uint32_t)n);
            }
            if (lane == 0) segCnt[seg] = __popcll(bal);
        }
    }
    __syncthreads();

    // ---- Segment counts -> exclusive offsets (wave-0 shfl scan) ----
    if (tid < 64) {
        int v = (lane < SEGW) ? segCnt[lane] : 0;
        #pragma unroll
        for (int d = 1; d < 64; d <<= 1) {
            const int o = __shfl_up(v, d);
            if (lane >= d) v += o;
        }
        if (lane < SEGW) offL[lane + 1] = v;
        if (lane == 0) offL[0] = 0;
    }
    __syncthreads();
    const int Mfull = offL[SEGW];
    const int M = Mfull < CAP ? Mfull : CAP;

    // ---- Gather segments -> contiguous keysL (binary search, all waves) ----
    for (int i = tid; i < CAP; i += BNTH) {
        uint64_t k = 0ull;
        if (i < M) {
            int lo = 0, hi = SEGW;
            while (hi - lo > 1) {
                const int mid = (lo + hi) >> 1;
                if (offL[mid] <= i) lo = mid; else hi = mid;
            }
            k = segKeys[lo][i - offL[lo]];
        }
        keysL[i] = k;
    }
    __syncthreads();

    // ---- Sort descending on wave 0 (registers; smallest sufficient net) ----
    if (tid < 64) {
        if (M > 1) {
            if (M <= 512) {
                double kd[8];
                #pragma unroll
                for (int s = 0; s < 8; ++s)
                    kd[s] = __longlong_as_double((long long)keysL[s * 64 + lane]);
                bitonic_desc<512>(kd, lane);
                #pragma unroll
                for (int s = 0; s < 8; ++s)
                    keysL[s * 64 + lane] = (uint64_t)__double_as_longlong(kd[s]);
            } else {
                double kd[16];
                #pragma unroll
                for (int s = 0; s < 16; ++s)
                    kd[s] = __longlong_as_double((long long)keysL[s * 64 + lane]);
                bitonic_desc<1024>(kd, lane);
                #pragma unroll
                for (int s = 0; s < 16; ++s)
                    keysL[s * 64 + lane] = (uint64_t)__double_as_longlong(kd[s]);
            }
        }
    }
    __syncthreads();

    // ---- Decode in SORTED order, all 4 waves (4x latency hiding) ----
    const float H = info[b * 3 + 0];
    const float W = info[b * 3 + 1];
    const float scale = info[b * 3 + 2];
    for (int i = tid; i < M; i += BNTH) {
        const uint64_t u = keysL[i];
        const int n = (int)(~(uint32_t)u);
        float o[4];
        decode_box(rois, pred, H, W, scale, b, n, c, N, C, o);
        boxL[i] = make_float4(o[0], o[1], o[2], o[3]);
        sarL[i] = (o[2] - o[0] + 1.0f) * (o[3] - o[1] + 1.0f);
    }
    __syncthreads();

    // ---- Scan NMS over sorted order on wave 0, 64 candidates per batch ----
    if (tid < 64) {
        float* ksc = kept_scores + (size_t)bx * MAXK;
        int kcount = 0;
        float4 cls_best = make_float4(0.f, 0.f, 0.f, 0.f);

        for (int s = 0; s * 64 < M && kcount < MAXK; ++s) {
            const int ii = s * 64 + lane;
            const bool valid = (ii < M);
            float cx1 = 0.f, cy1 = 0.f, cx2 = 0.f, cy2 = 0.f, car = 1.0f, csc = 0.f;
            if (valid) {
                const float4 cb4 = boxL[ii];
                cx1 = cb4.x; cy1 = cb4.y; cx2 = cb4.z; cy2 = cb4.w;
                car = sarL[ii];
                csc = __uint_as_float((uint32_t)(keysL[ii] >> 32));
            }
            // Pre-suppression vs already-kept boxes (uniform loop, pipelined).
            bool sup = !valid;
            for (int q = 0; q < kcount; ++q) {
                const float4 kb = keptL[q];
                const float kar = (kb.z - kb.x + 1.0f) * (kb.w - kb.y + 1.0f);
                const float ix1 = fmaxf(kb.x, cx1), iy1 = fmaxf(kb.y, cy1);
                const float ix2 = fminf(kb.z, cx2), iy2 = fminf(kb.w, cy2);
                const float iw = fmaxf(ix2 - ix1 + 1.0f, 0.0f);
                const float ih = fmaxf(iy2 - iy1 + 1.0f, 0.0f);
                const float inter = iw * ih;
                sup = sup || (inter / (kar + car - inter) > NMS_T);
            }
            uint64_t alive = ~__ballot(sup);
            // Intra-batch serial keep loop (sorted rank order == lane order).
            while (alive != 0ull && kcount < MAXK) {
                const int l = __builtin_ctzll(alive);      // highest-ranked alive
                const float kx1 = __shfl(cx1, l), ky1 = __shfl(cy1, l);
                const float kx2 = __shfl(cx2, l), ky2 = __shfl(cy2, l);
                const float kar = (kx2 - kx1 + 1.0f) * (ky2 - ky1 + 1.0f);
                if (lane == l) {
                    keptL[kcount] = make_float4(cx1, cy1, cx2, cy2);
                    ksc[kcount] = csc;
                }
                if (kcount == 0) cls_best = make_float4(kx1, ky1, kx2, ky2);
                const float ix1 = fmaxf(kx1, cx1), iy1 = fmaxf(ky1, cy1);
                const float ix2 = fminf(kx2, cx2), iy2 = fminf(ky2, cy2);
                const float iw = fmaxf(ix2 - ix1 + 1.0f, 0.0f);
                const float ih = fmaxf(iy2 - iy1 + 1.0f, 0.0f);
                const float inter = iw * ih;
                const bool s2 = (inter / (kar + car - inter) > NMS_T);
                alive &= ~__ballot(s2);
                alive &= ~(1ull << l);     // keeper always removed
                kcount++;
            }
        }

        if (lane == 0) {
            kcounts[bx] = kcount;
            float* cbp = cls_box + (size_t)bx * 4;
            cbp[0] = cls_best.x; cbp[1] = cls_best.y;
            cbp[2] = cls_best.z; cbp[3] = cls_best.w;
        }
    }
    __syncthreads();

    // ==== Tail v2: distributed select via per-image monotonic gate ====
    __threadfence();
    if (tid == 0) {
        const unsigned long long t = atomicAdd(&done_img[img], 1ull);
        selL = ((t % (unsigned long long)FG) ==
                (unsigned long long)(FG - 1)) ? 1 : 0;
    }
    __syncthreads();
    if (!selL) return;
    __threadfence();   // acquire: all class-blocks of this image visible

    // ---- Per-image select, ALL 256 threads, image = img ----
    float* stg = (float*)boxL;         // reuse 16 KB: FG*MAXK floats
    {
        const float* src = kept_scores + (size_t)img * FG * MAXK;
        for (int e = tid; e < FG * MAXK; e += BNTH) stg[e] = src[e];
        if (tid < FG) {
            selKc[tid] = kcounts[img * FG + tid];
            selCnt[tid] = 0;
        }
    }
    __syncthreads();
    if (tid < FG)
        selSc[tid] = (selKc[tid] > 0) ? stg[tid * MAXK] : -INFINITY;
    __syncthreads();

    // Count entries strictly greater than each class's best: 400 pairs over
    // 256 threads, 6-step binary search (desc lists -> prefix predicate).
    for (int p = tid; p < FG * FG; p += BNTH) {
        const int cc = p / FG, c2 = p % FG;
        const float sc = selSc[cc];
        const int k2 = selKc[c2];
        int cnt = 0;
        if (selKc[cc] > 0 && k2 > 0) {
            const float* lp = stg + c2 * MAXK;
            int lo = 0, hi = k2;
            while (lo < hi) {
                const int mid = (lo + hi) >> 1;
                const float v = lp[mid];
                const bool greater = (v > sc) || (v == sc && c2 < cc);
                if (greater) lo = mid + 1; else hi = mid;
            }
            cnt = lo;
        }
        if (cnt) atomicAdd(&selCnt[cc], cnt);
    }
    __syncthreads();

    // Wave 0: global-best reduce + emit per-class best_s/best_b.
    if (tid < 64) {
        const int kc_l = (lane < FG) ? selKc[lane] : 0;
        const float sv_l = (lane < FG) ? selSc[lane] : -INFINITY;
        uint32_t mu = 0u;
        if (lane < FG && kc_l > 0) {
            const uint32_t bb = __float_as_uint(sv_l);
            mu = (bb & 0x80000000u) ? ~bb : (bb | 0x80000000u);
        }
        uint64_t gkey = (mu == 0u) ? 0ull
                        : (((uint64_t)mu << 8) | (uint64_t)(255 - lane));
        #pragma unroll
        for (int m = 1; m < 64; m <<= 1) {
            const uint64_t o = __shfl_xor(gkey, m);
            if (o > gkey) gkey = o;
        }
        float4 gbox;
        if ((gkey >> 8) != 0ull) {
            const int g = 255 - (int)(gkey & 0xFFull);
            gbox = *(const float4*)(cls_box + ((size_t)img * FG + g) * 4);
        } else {
            float o[4];
            decode_box(rois, pred, H, W, scale, b, 0, 1, N, C, o);
            gbox = make_float4(o[0], o[1], o[2], o[3]);
        }
        if (lane < FG) {
            const bool in = (kc_l > 0 && selCnt[lane] < MAXK);
            best_s[img * FG + lane] = in ? sv_l : -INFINITY;
            float4 ob = in
                ? *(const float4*)(cls_box + ((size_t)img * FG + lane) * 4)
                : gbox;
            *(float4*)(best_b + ((size_t)img * FG + lane) * 4) = ob;
        }
    }
    __syncthreads();

    // ---- Global gate: last image-select performs the combine ----
    __threadfence();
    if (tid == 0) {
        const unsigned long long t2 = atomicAdd(done_all, 1ull);
        combL = ((t2 % (unsigned long long)nimg) ==
                 (unsigned long long)(nimg - 1)) ? 1 : 0;
    }
    __syncthreads();
    if (!combL) return;
    __threadfence();   // acquire: all images' best_s/best_b visible

    // ---- Combine: stage best_s to LDS, then per-image argmax + gather ----
    for (int e = tid; e < nimg * FG; e += BNTH) stg[e] = best_s[e];
    __syncthreads();
    if (tid < Bimg) {
        const int i = tid;
        float bj = 0.0f;
        int cls_ = 0;
        for (int cc = 0; cc < FG; ++cc) {
            const float v = stg[i * FG + cc] * stg[(Bimg + i) * FG + cc];
            if (cc == 0 || v > bj) { bj = v; cls_ = cc; }   // -inf*-inf=+inf ok
        }
        const float4 bA = *(const float4*)(best_b + ((size_t)i * FG + cls_) * 4);
        const float4 bB = *(const float4*)(best_b + ((size_t)(Bimg + i) * FG + cls_) * 4);
        out[i * 4 + 0] = bA.x; out[i * 4 + 1] = bA.y;
        out[i * 4 + 2] = bA.z; out[i * 4 + 3] = bA.w;
        out[Bimg * 4 + i * 4 + 0] = bB.x; out[Bimg * 4 + i * 4 + 1] = bB.y;
        out[Bimg * 4 + i * 4 + 2] = bB.z; out[Bimg * 4 + i * 4 + 3] = bB.w;
    }
}

extern "C" void kernel_launch(void* const* d_in, const int* in_sizes, int n_in,
                              void* d_out, int out_size, void* d_ws, size_t ws_size,
                              hipStream_t stream) {
    const float* rois_A = (const float*)d_in[0];
    const float* cls_A  = (const float*)d_in[1];
    const float* pred_A = (const float*)d_in[2];
    const float* info_A = (const float*)d_in[3];
    const float* rois_B = (const float*)d_in[4];
    const float* cls_B  = (const float*)d_in[5];
    const float* pred_B = (const float*)d_in[6];
    const float* info_B = (const float*)d_in[7];
    float* out = (float*)d_out;

    const int Bimg = in_sizes[3] / 3;                  // 8
    const int N    = in_sizes[0] / (Bimg * 5);         // 2000
    const int C    = in_sizes[1] / (Bimg * N);         // 21
    const int FG   = C - 1;                            // 20
    const int NSB  = 2 * Bimg * FG;                    // 320 tasks

    // Workspace.  All gate counters are MONOTONIC u64 (never reset): each
    // call adds exactly FG to done_img[i] and nimg to done_all, so the
    // trigger residue fires exactly once per call -- graph-replay safe.
    char* ws = (char*)d_ws;
    unsigned long long* done_img = (unsigned long long*)ws;     // [NIMG_MAX]
    unsigned long long* done_all = done_img + NIMG_MAX;
    size_t off = 512;
    float* kept_scores = (float*)(ws + off);               // [320][50]
    off += (size_t)NSB * MAXK * sizeof(float);
    int* kcounts = (int*)(ws + off);                       // [320]
    off += (size_t)NSB * sizeof(int);
    off = (off + 15) & ~(size_t)15;
    float* cls_box = (float*)(ws + off);                   // [320][4] 16B-aligned
    off += (size_t)NSB * 4 * sizeof(float);
    float* best_s = (float*)(ws + off);                    // [320]
    off += (size_t)NSB * sizeof(float);
    off = (off + 15) & ~(size_t)15;
    float* best_b = (float*)(ws + off);                    // [320][4] 16B-aligned

    nms_kernel<<<NSB, BNTH, 0, stream>>>(
        rois_A, cls_A, pred_A, info_A,
        rois_B, cls_B, pred_B, info_B,
        Bimg, N, C, kept_scores, kcounts, cls_box,
        done_img, done_all, best_s, best_b, out);
}

// Round 13
// 58.648 us; speedup vs baseline: 1.5381x; 1.0838x over previous
//
#include <hip/hip_runtime.h>
#include <stdint.h>
#include <math.h>

#define BNTH 256           // 4 waves
#define CAP 1024           // max candidates per class-task
#define MAXK 50
#define THRESH_F 0.05f
#define NMS_T 0.3f
#define SEGW_MAX 32        // 64-row segments per image (N <= 2048; problem: 32)
#define RMAX 8             // SEGW_MAX / 4 waves

// Decode one (image b, row n, class c) box exactly like the reference.
// (Arithmetic identical to the absmax-0.0 version -- do not reorder.)
__device__ __forceinline__ void decode_box(
    const float* __restrict__ rois, const float* __restrict__ pred,
    float H, float W, float scale,
    int b, int n, int c, int N, int C, float out[4])
{
    const float* r = rois + ((size_t)b * N + n) * 5;
    float bx1 = r[1], by1 = r[2], bx2 = r[3], by2 = r[4];
    float w  = bx2 - bx1 + 1.0f;
    float h  = by2 - by1 + 1.0f;
    float cx = bx1 + 0.5f * w;
    float cy = by1 + 0.5f * h;
    const float* d = pred + ((size_t)b * N + n) * 4 * C + 4 * c;
    float dx = d[0] * 0.1f, dy = d[1] * 0.1f;
    float dw = d[2] * 0.2f, dh = d[3] * 0.2f;
    float pcx = dx * w + cx;
    float pcy = dy * h + cy;
    float pw  = expf(dw) * w;
    float ph  = expf(dh) * h;
    float X1 = fminf(fmaxf(pcx - 0.5f * pw, 0.0f), W - 1.0f);
    float Y1 = fminf(fmaxf(pcy - 0.5f * ph, 0.0f), H - 1.0f);
    float X2 = fminf(fmaxf(pcx + 0.5f * pw, 0.0f), W - 1.0f);
    float Y2 = fminf(fmaxf(pcy + 0.5f * ph, 0.0f), H - 1.0f);
    out[0] = X1 / scale;
    out[1] = Y1 / scale;
    out[2] = X2 / scale;
    out[3] = Y2 / scale;
}

// Register bitonic sort, descending, over SN elements laid out as
// index i = s*64 + lane (slot-major), on ONE wave.  Keys are u64
// (score<<32|~row) reinterpreted as POSITIVE doubles (exponent normal,
// never NaN), so f64 fmax/fmin ordering == u64 ordering.
template<int SN>
__device__ __forceinline__ void bitonic_desc(double* kd, int lane)
{
    constexpr int NS = SN / 64;
    #pragma unroll
    for (int k = 2; k <= SN; k <<= 1) {
        #pragma unroll
        for (int j = k >> 1; j >= 1; j >>= 1) {
            if (j >= 64) {
                const int js = j >> 6;
                #pragma unroll
                for (int s = 0; s < NS; ++s) {
                    if ((s & js) == 0) {
                        const int sp = s | js;
                        const bool d = (((s << 6) & k) == 0);  // compile-time
                        const double a = kd[s], bb = kd[sp];
                        kd[s]  = d ? fmax(a, bb) : fmin(a, bb);
                        kd[sp] = d ? fmin(a, bb) : fmax(a, bb);
                    }
                }
            } else {
                #pragma unroll
                for (int s = 0; s < NS; ++s) {
                    const double o = __shfl_xor(kd[s], j);
                    const bool lower = (lane & j) == 0;
                    const bool d = ((((s << 6) | lane) & k) == 0);
                    const bool takeMax = (d == lower);
                    const double mx = fmax(kd[s], o);
                    const double mn = fmin(kd[s], o);
                    kd[s] = takeMax ? mx : mn;
                }
            }
        }
    }
}

// Kernel 1 (round-7 structure): one 4-wave block per (stream, image, class).
// PIPELINED collect (8 loads hoisted) -> shfl prefix scan -> gather ->
// wave-0 register bitonic sort -> all-wave decode -> wave-0 sorted-scan NMS
// with LDS-broadcast keeper (uniform index after ctz).
__global__ __launch_bounds__(BNTH, 1) void nms_kernel(
    const float* __restrict__ rois_A, const float* __restrict__ cls_A,
    const float* __restrict__ pred_A, const float* __restrict__ info_A,
    const float* __restrict__ rois_B, const float* __restrict__ cls_B,
    const float* __restrict__ pred_B, const float* __restrict__ info_B,
    int Bimg, int N, int C,
    float* __restrict__ kept_scores, int* __restrict__ kcounts,
    float* __restrict__ cls_box, int* __restrict__ sync_counter)
{
    const int FG = C - 1;
    const int bx = blockIdx.x;
    const int st  = bx / (Bimg * FG);
    const int rem = bx % (Bimg * FG);
    const int b = rem / FG;
    const int j = rem % FG;
    const int c = j + 1;
    const int tid = threadIdx.x;
    const int w = tid >> 6;
    const int lane = tid & 63;
    const int SEGW = (N + 63) >> 6;              // <= SEGW_MAX

    if (bx == 0 && tid == 0) *sync_counter = 0;  // ordered before kernel 2

    const float* rois = st ? rois_B : rois_A;
    const float* cls  = st ? cls_B  : cls_A;
    const float* pred = st ? pred_B : pred_A;
    const float* info = st ? info_B : info_A;

    __shared__ uint64_t segKeys[SEGW_MAX][64];
    __shared__ int segCnt[SEGW_MAX];
    __shared__ int offL[SEGW_MAX + 1];
    __shared__ uint64_t keysL[CAP];
    __shared__ float4 boxL[CAP];
    __shared__ float  sarL[CAP];
    __shared__ float4 keptL[MAXK];

    // ---- Collect, PIPELINED: all 8 strided loads issued before any ballot
    // (static unroll -> scv[] stays in VGPRs, loads overlap in flight). ----
    float scv[RMAX];
    #pragma unroll
    for (int r = 0; r < RMAX; ++r) {
        const int seg = w + 4 * r;
        const int n = seg * 64 + lane;
        scv[r] = 0.0f;
        if (seg < SEGW && n < N)
            scv[r] = cls[((size_t)b * N + n) * C + c];
    }
    #pragma unroll
    for (int r = 0; r < RMAX; ++r) {
        const int seg = w + 4 * r;
        if (seg < SEGW) {
            const int n = seg * 64 + lane;
            const bool val = scv[r] > THRESH_F;
            const uint64_t bal = __ballot(val);
            if (val) {
                const int slot = __popcll(bal & ((1ull << lane) - 1ull));
                segKeys[seg][slot] =
                    ((uint64_t)__float_as_uint(scv[r]) << 32) |
                    (uint32_t)(~(uint32_t)n);
            }
            if (lane == 0) segCnt[seg] = __popcll(bal);
        }
    }
    __syncthreads();

    // ---- Segment counts -> exclusive offsets (wave-0 shfl scan) ----
    if (tid < 64) {
        int v = (lane < SEGW) ? segCnt[lane] : 0;
        #pragma unroll
        for (int d = 1; d < 64; d <<= 1) {
            const int o = __shfl_up(v, d);
            if (lane >= d) v += o;
        }
        if (lane < SEGW) offL[lane + 1] = v;
        if (lane == 0) offL[0] = 0;
    }
    __syncthreads();
    const int Mfull = offL[SEGW];
    const int M = Mfull < CAP ? Mfull : CAP;

    // ---- Gather segments -> contiguous keysL (binary search, all waves) ----
    for (int i = tid; i < CAP; i += BNTH) {
        uint64_t k = 0ull;
        if (i < M) {
            int lo = 0, hi = SEGW;
            while (hi - lo > 1) {
                const int mid = (lo + hi) >> 1;
                if (offL[mid] <= i) lo = mid; else hi = mid;
            }
            k = segKeys[lo][i - offL[lo]];
        }
        keysL[i] = k;
    }
    __syncthreads();

    // ---- Sort descending on wave 0 (registers; smallest sufficient net) ----
    if (tid < 64) {
        if (M > 1) {
            if (M <= 512) {
                double kd[8];
                #pragma unroll
                for (int s = 0; s < 8; ++s)
                    kd[s] = __longlong_as_double((long long)keysL[s * 64 + lane]);
                bitonic_desc<512>(kd, lane);
                #pragma unroll
                for (int s = 0; s < 8; ++s)
                    keysL[s * 64 + lane] = (uint64_t)__double_as_longlong(kd[s]);
            } else {
                double kd[16];
                #pragma unroll
                for (int s = 0; s < 16; ++s)
                    kd[s] = __longlong_as_double((long long)keysL[s * 64 + lane]);
                bitonic_desc<1024>(kd, lane);
                #pragma unroll
                for (int s = 0; s < 16; ++s)
                    keysL[s * 64 + lane] = (uint64_t)__double_as_longlong(kd[s]);
            }
        }
    }
    __syncthreads();

    // ---- Decode in SORTED order, all 4 waves (4x latency hiding) ----
    const float H = info[b * 3 + 0];
    const float W = info[b * 3 + 1];
    const float scale = info[b * 3 + 2];
    for (int i = tid; i < M; i += BNTH) {
        const uint64_t u = keysL[i];
        const int n = (int)(~(uint32_t)u);
        float o[4];
        decode_box(rois, pred, H, W, scale, b, n, c, N, C, o);
        boxL[i] = make_float4(o[0], o[1], o[2], o[3]);
        sarL[i] = (o[2] - o[0] + 1.0f) * (o[3] - o[1] + 1.0f);
    }
    __syncthreads();

    // ---- Scan NMS over sorted order on wave 0, 64 candidates per batch ----
    if (tid < 64) {
        float* ksc = kept_scores + (size_t)bx * MAXK;
        int kcount = 0;
        float4 cls_best = make_float4(0.f, 0.f, 0.f, 0.f);

        for (int s = 0; s * 64 < M && kcount < MAXK; ++s) {
            const int ii = s * 64 + lane;
            const bool valid = (ii < M);
            float cx1 = 0.f, cy1 = 0.f, cx2 = 0.f, cy2 = 0.f, car = 1.0f, csc = 0.f;
            if (valid) {
                const float4 cb4 = boxL[ii];
                cx1 = cb4.x; cy1 = cb4.y; cx2 = cb4.z; cy2 = cb4.w;
                car = sarL[ii];
                csc = __uint_as_float((uint32_t)(keysL[ii] >> 32));
            }
            // Pre-suppression vs already-kept boxes (uniform loop, pipelined).
            bool sup = !valid;
            for (int q = 0; q < kcount; ++q) {
                const float4 kb = keptL[q];
                const float kar = (kb.z - kb.x + 1.0f) * (kb.w - kb.y + 1.0f);
                const float ix1 = fmaxf(kb.x, cx1), iy1 = fmaxf(kb.y, cy1);
                const float ix2 = fminf(kb.z, cx2), iy2 = fminf(kb.w, cy2);
                const float iw = fmaxf(ix2 - ix1 + 1.0f, 0.0f);
                const float ih = fmaxf(iy2 - iy1 + 1.0f, 0.0f);
                const float inter = iw * ih;
                sup = sup || (inter / (kar + car - inter) > NMS_T);
            }
            uint64_t alive = ~__ballot(sup);
            // Intra-batch serial keep loop.  Keeper index (s*64+l) is wave-
            // uniform after ctz -> LDS broadcast read replaces 4 shfls.
            while (alive != 0ull && kcount < MAXK) {
                const int l = __builtin_ctzll(alive);      // highest-ranked alive
                const int ki = s * 64 + l;
                const float4 kb = boxL[ki];                // uniform broadcast
                const float kar = sarL[ki];
                if (lane == l) {
                    keptL[kcount] = make_float4(cx1, cy1, cx2, cy2);
                    ksc[kcount] = csc;
                }
                if (kcount == 0) cls_best = kb;            // rank-0 keep
                const float ix1 = fmaxf(kb.x, cx1), iy1 = fmaxf(kb.y, cy1);
                const float ix2 = fminf(kb.z, cx2), iy2 = fminf(kb.w, cy2);
                const float iw = fmaxf(ix2 - ix1 + 1.0f, 0.0f);
                const float ih = fmaxf(iy2 - iy1 + 1.0f, 0.0f);
                const float inter = iw * ih;
                const bool s2 = (inter / (kar + car - inter) > NMS_T);
                alive &= ~__ballot(s2);
                alive &= ~(1ull << l);     // keeper always removed
                kcount++;
            }
        }

        if (lane == 0) {
            kcounts[bx] = kcount;
            float* cbp = cls_box + (size_t)bx * 4;
            cbp[0] = cls_best.x; cbp[1] = cls_best.y;
            cbp[2] = cls_best.z; cbp[3] = cls_best.w;
        }
    }
}

// Kernel 2: one block per (stream, image): global top-50 cap via branchless
// full count of strictly-greater entries, then the LAST finished block does
// the joint A*B argmax + output gather (device-scope atomic gate).
__global__ __launch_bounds__(64) void select_combine(
    const float* __restrict__ kept_scores, const int* __restrict__ kcounts,
    const float* __restrict__ cls_box,
    const float* __restrict__ rois_A, const float* __restrict__ pred_A,
    const float* __restrict__ info_A,
    const float* __restrict__ rois_B, const float* __restrict__ pred_B,
    const float* __restrict__ info_B,
    int Bimg, int N, int C,
    float* best_s, float* best_b, int* sync_counter, float* __restrict__ out)
{
    const int FG = C - 1;
    const int bx = blockIdx.x;           // st*Bimg + b
    const int st = bx / Bimg;
    const int b  = bx % Bimg;
    const int tid = threadIdx.x;

    __shared__ float sk[20][MAXK];
    __shared__ int   skc[20];
    __shared__ float stopv[20];
    __shared__ int   cnt20[20];
    __shared__ int   inflag[20];
    __shared__ float gbox[4];
    __shared__ int   amlast;

    const size_t base = (size_t)bx * FG;
    for (int i = tid; i < FG * MAXK; i += 64)
        sk[i / MAXK][i % MAXK] = kept_scores[base * MAXK + i];
    if (tid < FG) {
        skc[tid] = kcounts[base + tid];
        cnt20[tid] = 0;
    }
    __syncthreads();
    if (tid < FG)
        stopv[tid] = (skc[tid] > 0) ? sk[tid][0] : -INFINITY;
    __syncthreads();

    // Count entries strictly greater than each class's best (400 pairs over
    // 64 lanes, branchless inner loop -> pipelined LDS reads).
    for (int p = tid; p < FG * FG; p += 64) {
        const int cc = p / FG;     // candidate class
        const int c2 = p % FG;     // donor class
        const float sc = stopv[cc];
        const int k2 = skc[c2];
        int cnt = 0;
        if (skc[cc] > 0) {
            #pragma unroll 5
            for (int k = 0; k < k2; ++k) {
                const float v = sk[c2][k];
                cnt += ((v > sc) || (v == sc && c2 < cc)) ? 1 : 0;
            }
        }
        if (cnt) atomicAdd(&cnt20[cc], cnt);
    }
    __syncthreads();
    if (tid < FG)
        inflag[tid] = (skc[tid] > 0 && cnt20[tid] < MAXK) ? 1 : 0;
    __syncthreads();

    if (tid == 0) {
        int g = -1;
        float bs = -INFINITY;
        for (int c2 = 0; c2 < FG; ++c2)
            if (skc[c2] > 0 && stopv[c2] > bs) { bs = stopv[c2]; g = c2; }
        if (g >= 0) {
            const float* cbp = cls_box + (base + g) * 4;
            gbox[0] = cbp[0]; gbox[1] = cbp[1]; gbox[2] = cbp[2]; gbox[3] = cbp[3];
        } else {
            const float* rois = st ? rois_B : rois_A;
            const float* pred = st ? pred_B : pred_A;
            const float* info = st ? info_B : info_A;
            float o[4];
            decode_box(rois, pred, info[b * 3], info[b * 3 + 1], info[b * 3 + 2],
                       b, 0, 1, N, C, o);
            gbox[0] = o[0]; gbox[1] = o[1]; gbox[2] = o[2]; gbox[3] = o[3];
        }
    }
    __syncthreads();

    if (tid < FG) {
        const int in = inflag[tid];
        best_s[base + tid] = in ? stopv[tid] : -INFINITY;
        float* ob = best_b + (base + tid) * 4;
        if (in) {
            const float* cbp = cls_box + (base + tid) * 4;
            ob[0] = cbp[0]; ob[1] = cbp[1]; ob[2] = cbp[2]; ob[3] = cbp[3];
        } else {
            ob[0] = gbox[0]; ob[1] = gbox[1]; ob[2] = gbox[2]; ob[3] = gbox[3];
        }
    }

    // ---- last-done block performs the combine ----
    __threadfence();
    if (tid == 0) amlast = (atomicAdd(sync_counter, 1) == 2 * Bimg - 1);
    __syncthreads();
    if (amlast) {
        __threadfence();   // acquire: other blocks' best_s/best_b now visible
        if (tid < Bimg) {
            const int i = tid;
            const float* sA = best_s + (size_t)i * FG;
            const float* sB = best_s + (size_t)(Bimg + i) * FG;
            float bj = 0.0f;
            int cls = 0;
            for (int cc = 0; cc < FG; ++cc) {
                const float v = sA[cc] * sB[cc];   // IEEE: -inf*-inf=+inf
                if (cc == 0 || v > bj) { bj = v; cls = cc; }
            }
            const float* bA = best_b + ((size_t)i * FG + cls) * 4;
            const float* bB = best_b + ((size_t)(Bimg + i) * FG + cls) * 4;
            for (int k = 0; k < 4; ++k) {
                out[i * 4 + k]            = bA[k];
                out[Bimg * 4 + i * 4 + k] = bB[k];
            }
        }
    }
}

extern "C" void kernel_launch(void* const* d_in, const int* in_sizes, int n_in,
                              void* d_out, int out_size, void* d_ws, size_t ws_size,
                              hipStream_t stream) {
    const float* rois_A = (const float*)d_in[0];
    const float* cls_A  = (const float*)d_in[1];
    const float* pred_A = (const float*)d_in[2];
    const float* info_A = (const float*)d_in[3];
    const float* rois_B = (const float*)d_in[4];
    const float* cls_B  = (const float*)d_in[5];
    const float* pred_B = (const float*)d_in[6];
    const float* info_B = (const float*)d_in[7];
    float* out = (float*)d_out;

    const int Bimg = in_sizes[3] / 3;                  // 8
    const int N    = in_sizes[0] / (Bimg * 5);         // 2000
    const int C    = in_sizes[1] / (Bimg * N);         // 21
    const int FG   = C - 1;                            // 20
    const int NSB  = 2 * Bimg * FG;                    // 320 tasks

    // Workspace (everything overwritten each call; no resets needed).
    char* ws = (char*)d_ws;
    int* sync_counter = (int*)ws;
    size_t off = 256;
    float* kept_scores = (float*)(ws + off);               // [320][50]
    off += (size_t)NSB * MAXK * sizeof(float);
    int* kcounts = (int*)(ws + off);                       // [320]
    off += (size_t)NSB * sizeof(int);
    float* cls_box = (float*)(ws + off);                   // [320][4]
    off += (size_t)NSB * 4 * sizeof(float);
    float* best_s = (float*)(ws + off);                    // [320]
    off += (size_t)NSB * sizeof(float);
    float* best_b = (float*)(ws + off);                    // [320][4]

    nms_kernel<<<NSB, BNTH, 0, stream>>>(
        rois_A, cls_A, pred_A, info_A,
        rois_B, cls_B, pred_B, info_B,
        Bimg, N, C, kept_scores, kcounts, cls_box, sync_counter);

    select_combine<<<2 * Bimg, 64, 0, stream>>>(
        kept_scores, kcounts, cls_box,
        rois_A, pred_A, info_A, rois_B, pred_B, info_B,
        Bimg, N, C, best_s, best_b, sync_counter, out);
}

// Round 14
// 52.324 us; speedup vs baseline: 1.7240x; 1.1209x over previous
//
#include <hip/hip_runtime.h>
#include <stdint.h>
#include <math.h>

#define BNTH 256           // 4 waves
#define CAP 1024           // max candidates per class-task
#define MAXK 50
#define THRESH_F 0.05f
#define NMS_T 0.3f
#define SEGW_MAX 32        // 64-row segments per image (N <= 2048; problem: 32)
#define RMAX 8             // SEGW_MAX / 4 waves

// Decode one (image b, row n, class c) box exactly like the reference.
// (Arithmetic identical to the absmax-0.0 version -- do not reorder.)
__device__ __forceinline__ void decode_box(
    const float* __restrict__ rois, const float* __restrict__ pred,
    float H, float W, float scale,
    int b, int n, int c, int N, int C, float out[4])
{
    const float* r = rois + ((size_t)b * N + n) * 5;
    float bx1 = r[1], by1 = r[2], bx2 = r[3], by2 = r[4];
    float w  = bx2 - bx1 + 1.0f;
    float h  = by2 - by1 + 1.0f;
    float cx = bx1 + 0.5f * w;
    float cy = by1 + 0.5f * h;
    const float* d = pred + ((size_t)b * N + n) * 4 * C + 4 * c;
    float dx = d[0] * 0.1f, dy = d[1] * 0.1f;
    float dw = d[2] * 0.2f, dh = d[3] * 0.2f;
    float pcx = dx * w + cx;
    float pcy = dy * h + cy;
    float pw  = expf(dw) * w;
    float ph  = expf(dh) * h;
    float X1 = fminf(fmaxf(pcx - 0.5f * pw, 0.0f), W - 1.0f);
    float Y1 = fminf(fmaxf(pcy - 0.5f * ph, 0.0f), H - 1.0f);
    float X2 = fminf(fmaxf(pcx + 0.5f * pw, 0.0f), W - 1.0f);
    float Y2 = fminf(fmaxf(pcy + 0.5f * ph, 0.0f), H - 1.0f);
    out[0] = X1 / scale;
    out[1] = Y1 / scale;
    out[2] = X2 / scale;
    out[3] = Y2 / scale;
}

// Register bitonic sort, descending, over SN elements laid out as
// index i = s*64 + lane (slot-major), on ONE wave.  Keys are u64
// (score<<32|~slot) reinterpreted as POSITIVE doubles (exponent normal,
// never NaN), so f64 fmax/fmin ordering == u64 ordering.
template<int SN>
__device__ __forceinline__ void bitonic_desc(double* kd, int lane)
{
    constexpr int NS = SN / 64;
    #pragma unroll
    for (int k = 2; k <= SN; k <<= 1) {
        #pragma unroll
        for (int j = k >> 1; j >= 1; j >>= 1) {
            if (j >= 64) {
                const int js = j >> 6;
                #pragma unroll
                for (int s = 0; s < NS; ++s) {
                    if ((s & js) == 0) {
                        const int sp = s | js;
                        const bool d = (((s << 6) & k) == 0);  // compile-time
                        const double a = kd[s], bb = kd[sp];
                        kd[s]  = d ? fmax(a, bb) : fmin(a, bb);
                        kd[sp] = d ? fmin(a, bb) : fmax(a, bb);
                    }
                }
            } else {
                #pragma unroll
                for (int s = 0; s < NS; ++s) {
                    const double o = __shfl_xor(kd[s], j);
                    const bool lower = (lane & j) == 0;
                    const bool d = ((((s << 6) | lane) & k) == 0);
                    const bool takeMax = (d == lower);
                    const double mx = fmax(kd[s], o);
                    const double mn = fmin(kd[s], o);
                    kd[s] = takeMax ? mx : mn;
                }
            }
        }
    }
}

// Kernel 1: one 4-wave block per (stream, image, class).
// Pipelined collect -> shfl prefix scan -> gather (keys carry ~slot; rowsL
// maps slot->row) -> [wave 0: register bitonic sort  ||  waves 1-3: decode
// all boxes by slot] -> all-wave permute boxes into sorted order -> wave-0
// sorted-scan NMS.
__global__ __launch_bounds__(BNTH, 1) void nms_kernel(
    const float* __restrict__ rois_A, const float* __restrict__ cls_A,
    const float* __restrict__ pred_A, const float* __restrict__ info_A,
    const float* __restrict__ rois_B, const float* __restrict__ cls_B,
    const float* __restrict__ pred_B, const float* __restrict__ info_B,
    int Bimg, int N, int C,
    float* __restrict__ kept_scores, int* __restrict__ kcounts,
    float* __restrict__ cls_box, int* __restrict__ sync_counter)
{
    const int FG = C - 1;
    const int bx = blockIdx.x;
    const int st  = bx / (Bimg * FG);
    const int rem = bx % (Bimg * FG);
    const int b = rem / FG;
    const int j = rem % FG;
    const int c = j + 1;
    const int tid = threadIdx.x;
    const int w = tid >> 6;
    const int lane = tid & 63;
    const int SEGW = (N + 63) >> 6;              // <= SEGW_MAX

    if (bx == 0 && tid == 0) *sync_counter = 0;  // ordered before kernel 2

    const float* rois = st ? rois_B : rois_A;
    const float* cls  = st ? cls_B  : cls_A;
    const float* pred = st ? pred_B : pred_A;
    const float* info = st ? info_B : info_A;

    __shared__ uint64_t segKeys[SEGW_MAX][64];   // 16 KB; reused as boxS later
    __shared__ int segCnt[SEGW_MAX];
    __shared__ int offL[SEGW_MAX + 1];
    __shared__ uint64_t keysL[CAP];
    __shared__ unsigned short rowsL[CAP];
    __shared__ float4 boxL[CAP];                 // slot-indexed boxes
    __shared__ float4 keptL[MAXK];

    float4* boxS = (float4*)segKeys;             // sorted-order boxes (16 KB)

    // ---- Collect, PIPELINED: all 8 strided loads issued before ballots ----
    float scv[RMAX];
    #pragma unroll
    for (int r = 0; r < RMAX; ++r) {
        const int seg = w + 4 * r;
        const int n = seg * 64 + lane;
        scv[r] = 0.0f;
        if (seg < SEGW && n < N)
            scv[r] = cls[((size_t)b * N + n) * C + c];
    }
    #pragma unroll
    for (int r = 0; r < RMAX; ++r) {
        const int seg = w + 4 * r;
        if (seg < SEGW) {
            const int n = seg * 64 + lane;
            const bool val = scv[r] > THRESH_F;
            const uint64_t bal = __ballot(val);
            if (val) {
                const int slot = __popcll(bal & ((1ull << lane) - 1ull));
                segKeys[seg][slot] =
                    ((uint64_t)__float_as_uint(scv[r]) << 32) |
                    (uint32_t)(~(uint32_t)n);
            }
            if (lane == 0) segCnt[seg] = __popcll(bal);
        }
    }
    __syncthreads();

    // ---- Segment counts -> exclusive offsets (wave-0 shfl scan) ----
    if (tid < 64) {
        int v = (lane < SEGW) ? segCnt[lane] : 0;
        #pragma unroll
        for (int d = 1; d < 64; d <<= 1) {
            const int o = __shfl_up(v, d);
            if (lane >= d) v += o;
        }
        if (lane < SEGW) offL[lane + 1] = v;
        if (lane == 0) offL[0] = 0;
    }
    __syncthreads();
    const int Mfull = offL[SEGW];
    const int M = Mfull < CAP ? Mfull : CAP;

    // ---- Gather: keysL[i] = (score<<32)|~i, rowsL[i] = row.  Slot order ==
    // row order, so ~slot tie-breaking == reference ~row tie-breaking. ----
    for (int i = tid; i < CAP; i += BNTH) {
        uint64_t k = 0ull;
        if (i < M) {
            int lo = 0, hi = SEGW;
            while (hi - lo > 1) {
                const int mid = (lo + hi) >> 1;
                if (offL[mid] <= i) lo = mid; else hi = mid;
            }
            const uint64_t u = segKeys[lo][i - offL[lo]];
            rowsL[i] = (unsigned short)(~(uint32_t)u);
            k = (u & 0xFFFFFFFF00000000ull) | (uint32_t)(~(uint32_t)i);
        }
        keysL[i] = k;
    }
    __syncthreads();

    const float H = info[b * 3 + 0];
    const float W = info[b * 3 + 1];
    const float scale = info[b * 3 + 2];

    // ---- OVERLAPPED: wave 0 sorts keys (registers) while waves 1-3 decode
    // all M boxes into boxL[slot] (slot-indexed; independent of the sort) ----
    if (tid < 64) {
        if (M > 1) {
            if (M <= 512) {
                double kd[8];
                #pragma unroll
                for (int s = 0; s < 8; ++s)
                    kd[s] = __longlong_as_double((long long)keysL[s * 64 + lane]);
                bitonic_desc<512>(kd, lane);
                #pragma unroll
                for (int s = 0; s < 8; ++s)
                    keysL[s * 64 + lane] = (uint64_t)__double_as_longlong(kd[s]);
            } else {
                double kd[16];
                #pragma unroll
                for (int s = 0; s < 16; ++s)
                    kd[s] = __longlong_as_double((long long)keysL[s * 64 + lane]);
                bitonic_desc<1024>(kd, lane);
                #pragma unroll
                for (int s = 0; s < 16; ++s)
                    keysL[s * 64 + lane] = (uint64_t)__double_as_longlong(kd[s]);
            }
        }
    } else {
        for (int i = tid - 64; i < M; i += BNTH - 64) {
            const int n = rowsL[i];
            float o[4];
            decode_box(rois, pred, H, W, scale, b, n, c, N, C, o);
            boxL[i] = make_float4(o[0], o[1], o[2], o[3]);
        }
    }
    __syncthreads();

    // ---- Permute boxes into sorted order (all waves, one LDS pass) ----
    for (int i = tid; i < M; i += BNTH) {
        const int slot = (int)(~(uint32_t)keysL[i]) & (CAP - 1);
        boxS[i] = boxL[slot];
    }
    __syncthreads();

    // ---- Scan NMS over sorted order on wave 0, 64 candidates per batch ----
    if (tid < 64) {
        float* ksc = kept_scores + (size_t)bx * MAXK;
        int kcount = 0;
        float4 cls_best = make_float4(0.f, 0.f, 0.f, 0.f);

        for (int s = 0; s * 64 < M && kcount < MAXK; ++s) {
            const int ii = s * 64 + lane;
            const bool valid = (ii < M);
            float cx1 = 0.f, cy1 = 0.f, cx2 = 0.f, cy2 = 0.f, car = 1.0f, csc = 0.f;
            if (valid) {
                const float4 cb4 = boxS[ii];
                cx1 = cb4.x; cy1 = cb4.y; cx2 = cb4.z; cy2 = cb4.w;
                car = (cx2 - cx1 + 1.0f) * (cy2 - cy1 + 1.0f);
                csc = __uint_as_float((uint32_t)(keysL[ii] >> 32));
            }
            // Pre-suppression vs already-kept boxes (uniform loop, pipelined).
            bool sup = !valid;
            for (int q = 0; q < kcount; ++q) {
                const float4 kb = keptL[q];
                const float kar = (kb.z - kb.x + 1.0f) * (kb.w - kb.y + 1.0f);
                const float ix1 = fmaxf(kb.x, cx1), iy1 = fmaxf(kb.y, cy1);
                const float ix2 = fminf(kb.z, cx2), iy2 = fminf(kb.w, cy2);
                const float iw = fmaxf(ix2 - ix1 + 1.0f, 0.0f);
                const float ih = fmaxf(iy2 - iy1 + 1.0f, 0.0f);
                const float inter = iw * ih;
                sup = sup || (inter / (kar + car - inter) > NMS_T);
            }
            uint64_t alive = ~__ballot(sup);
            // Intra-batch serial keep loop.  Keeper index (s*64+l) is wave-
            // uniform after ctz -> LDS broadcast read.
            while (alive != 0ull && kcount < MAXK) {
                const int l = __builtin_ctzll(alive);      // highest-ranked alive
                const int ki = s * 64 + l;
                const float4 kb = boxS[ki];                // uniform broadcast
                const float kar = (kb.z - kb.x + 1.0f) * (kb.w - kb.y + 1.0f);
                if (lane == l) {
                    keptL[kcount] = make_float4(cx1, cy1, cx2, cy2);
                    ksc[kcount] = csc;
                }
                if (kcount == 0) cls_best = kb;            // rank-0 keep
                const float ix1 = fmaxf(kb.x, cx1), iy1 = fmaxf(kb.y, cy1);
                const float ix2 = fminf(kb.z, cx2), iy2 = fminf(kb.w, cy2);
                const float iw = fmaxf(ix2 - ix1 + 1.0f, 0.0f);
                const float ih = fmaxf(iy2 - iy1 + 1.0f, 0.0f);
                const float inter = iw * ih;
                const bool s2 = (inter / (kar + car - inter) > NMS_T);
                alive &= ~__ballot(s2);
                alive &= ~(1ull << l);     // keeper always removed
                kcount++;
            }
        }

        if (lane == 0) {
            kcounts[bx] = kcount;
            float* cbp = cls_box + (size_t)bx * 4;
            cbp[0] = cls_best.x; cbp[1] = cls_best.y;
            cbp[2] = cls_best.z; cbp[3] = cls_best.w;
        }
    }
}

// Kernel 2: one block per (stream, image): global top-50 cap via 6-step
// binary-search count (desc lists -> prefix predicate -> lower bound ==
// exact count; proven rounds 10/11), then the LAST finished block does the
// joint A*B argmax + output gather (device-scope atomic gate).
__global__ __launch_bounds__(64) void select_combine(
    const float* __restrict__ kept_scores, const int* __restrict__ kcounts,
    const float* __restrict__ cls_box,
    const float* __restrict__ rois_A, const float* __restrict__ pred_A,
    const float* __restrict__ info_A,
    const float* __restrict__ rois_B, const float* __restrict__ pred_B,
    const float* __restrict__ info_B,
    int Bimg, int N, int C,
    float* best_s, float* best_b, int* sync_counter, float* __restrict__ out)
{
    const int FG = C - 1;
    const int bx = blockIdx.x;           // st*Bimg + b
    const int st = bx / Bimg;
    const int b  = bx % Bimg;
    const int tid = threadIdx.x;

    __shared__ float sk[20][MAXK];
    __shared__ int   skc[20];
    __shared__ float stopv[20];
    __shared__ int   cnt20[20];
    __shared__ int   inflag[20];
    __shared__ float gbox[4];
    __shared__ int   amlast;

    const size_t base = (size_t)bx * FG;
    for (int i = tid; i < FG * MAXK; i += 64)
        sk[i / MAXK][i % MAXK] = kept_scores[base * MAXK + i];
    if (tid < FG) {
        skc[tid] = kcounts[base + tid];
        cnt20[tid] = 0;
    }
    __syncthreads();
    if (tid < FG)
        stopv[tid] = (skc[tid] > 0) ? sk[tid][0] : -INFINITY;
    __syncthreads();

    // Count entries strictly greater than each class's best: 400 pairs over
    // 64 lanes, 6-step binary search per pair.
    for (int p = tid; p < FG * FG; p += 64) {
        const int cc = p / FG;     // candidate class
        const int c2 = p % FG;     // donor class
        const float sc = stopv[cc];
        const int k2 = skc[c2];
        int cnt = 0;
        if (skc[cc] > 0 && k2 > 0) {
            const float* lp = &sk[c2][0];
            int lo = 0, hi = k2;
            while (lo < hi) {
                const int mid = (lo + hi) >> 1;
                const float v = lp[mid];
                const bool greater = (v > sc) || (v == sc && c2 < cc);
                if (greater) lo = mid + 1; else hi = mid;
            }
            cnt = lo;
        }
        if (cnt) atomicAdd(&cnt20[cc], cnt);
    }
    __syncthreads();
    if (tid < FG)
        inflag[tid] = (skc[tid] > 0 && cnt20[tid] < MAXK) ? 1 : 0;
    __syncthreads();

    if (tid == 0) {
        int g = -1;
        float bs = -INFINITY;
        for (int c2 = 0; c2 < FG; ++c2)
            if (skc[c2] > 0 && stopv[c2] > bs) { bs = stopv[c2]; g = c2; }
        if (g >= 0) {
            const float* cbp = cls_box + (base + g) * 4;
            gbox[0] = cbp[0]; gbox[1] = cbp[1]; gbox[2] = cbp[2]; gbox[3] = cbp[3];
        } else {
            const float* rois = st ? rois_B : rois_A;
            const float* pred = st ? pred_B : pred_A;
            const float* info = st ? info_B : info_A;
            float o[4];
            decode_box(rois, pred, info[b * 3], info[b * 3 + 1], info[b * 3 + 2],
                       b, 0, 1, N, C, o);
            gbox[0] = o[0]; gbox[1] = o[1]; gbox[2] = o[2]; gbox[3] = o[3];
        }
    }
    __syncthreads();

    if (tid < FG) {
        const int in = inflag[tid];
        best_s[base + tid] = in ? stopv[tid] : -INFINITY;
        float* ob = best_b + (base + tid) * 4;
        if (in) {
            const float* cbp = cls_box + (base + tid) * 4;
            ob[0] = cbp[0]; ob[1] = cbp[1]; ob[2] = cbp[2]; ob[3] = cbp[3];
        } else {
            ob[0] = gbox[0]; ob[1] = gbox[1]; ob[2] = gbox[2]; ob[3] = gbox[3];
        }
    }

    // ---- last-done block performs the combine ----
    __threadfence();
    if (tid == 0) amlast = (atomicAdd(sync_counter, 1) == 2 * Bimg - 1);
    __syncthreads();
    if (amlast) {
        __threadfence();   // acquire: other blocks' best_s/best_b now visible
        if (tid < Bimg) {
            const int i = tid;
            const float* sA = best_s + (size_t)i * FG;
            const float* sB = best_s + (size_t)(Bimg + i) * FG;
            float bj = 0.0f;
            int cls = 0;
            for (int cc = 0; cc < FG; ++cc) {
                const float v = sA[cc] * sB[cc];   // IEEE: -inf*-inf=+inf
                if (cc == 0 || v > bj) { bj = v; cls = cc; }
            }
            const float* bA = best_b + ((size_t)i * FG + cls) * 4;
            const float* bB = best_b + ((size_t)(Bimg + i) * FG + cls) * 4;
            for (int k = 0; k < 4; ++k) {
                out[i * 4 + k]            = bA[k];
                out[Bimg * 4 + i * 4 + k] = bB[k];
            }
        }
    }
}

extern "C" void kernel_launch(void* const* d_in, const int* in_sizes, int n_in,
                              void* d_out, int out_size, void* d_ws, size_t ws_size,
                              hipStream_t stream) {
    const float* rois_A = (const float*)d_in[0];
    const float* cls_A  = (const float*)d_in[1];
    const float* pred_A = (const float*)d_in[2];
    const float* info_A = (const float*)d_in[3];
    const float* rois_B = (const float*)d_in[4];
    const float* cls_B  = (const float*)d_in[5];
    const float* pred_B = (const float*)d_in[6];
    const float* info_B = (const float*)d_in[7];
    float* out = (float*)d_out;

    const int Bimg = in_sizes[3] / 3;                  // 8
    const int N    = in_sizes[0] / (Bimg * 5);         // 2000
    const int C    = in_sizes[1] / (Bimg * N);         // 21
    const int FG   = C - 1;                            // 20
    const int NSB  = 2 * Bimg * FG;                    // 320 tasks

    // Workspace (everything overwritten each call; no resets needed).
    char* ws = (char*)d_ws;
    int* sync_counter = (int*)ws;
    size_t off = 256;
    float* kept_scores = (float*)(ws + off);               // [320][50]
    off += (size_t)NSB * MAXK * sizeof(float);
    int* kcounts = (int*)(ws + off);                       // [320]
    off += (size_t)NSB * sizeof(int);
    float* cls_box = (float*)(ws + off);                   // [320][4]
    off += (size_t)NSB * 4 * sizeof(float);
    float* best_s = (float*)(ws + off);                    // [320]
    off += (size_t)NSB * sizeof(float);
    float* best_b = (float*)(ws + off);                    // [320][4]

    nms_kernel<<<NSB, BNTH, 0, stream>>>(
        rois_A, cls_A, pred_A, info_A,
        rois_B, cls_B, pred_B, info_B,
        Bimg, N, C, kept_scores, kcounts, cls_box, sync_counter);

    select_combine<<<2 * Bimg, 64, 0, stream>>>(
        kept_scores, kcounts, cls_box,
        rois_A, pred_A, info_A, rois_B, pred_B, info_B,
        Bimg, N, C, best_s, best_b, sync_counter, out);
}

// Round 15
// 52.016 us; speedup vs baseline: 1.7342x; 1.0059x over previous
//
#include <hip/hip_runtime.h>
#include <stdint.h>
#include <math.h>

#define BNTH 256           // 4 waves
#define CAP 1024           // max candidates per class-task
#define MAXK 50
#define THRESH_F 0.05f
#define NMS_T 0.3f
#define SEGW_MAX 32        // 64-row segments per image (N <= 2048; problem: 32)
#define RMAX 8             // SEGW_MAX / 4 waves

// Decode one (image b, row n, class c) box exactly like the reference.
// (Arithmetic identical to the absmax-0.0 version -- do not reorder.)
__device__ __forceinline__ void decode_box(
    const float* __restrict__ rois, const float* __restrict__ pred,
    float H, float W, float scale,
    int b, int n, int c, int N, int C, float out[4])
{
    const float* r = rois + ((size_t)b * N + n) * 5;
    float bx1 = r[1], by1 = r[2], bx2 = r[3], by2 = r[4];
    float w  = bx2 - bx1 + 1.0f;
    float h  = by2 - by1 + 1.0f;
    float cx = bx1 + 0.5f * w;
    float cy = by1 + 0.5f * h;
    const float* d = pred + ((size_t)b * N + n) * 4 * C + 4 * c;
    float dx = d[0] * 0.1f, dy = d[1] * 0.1f;
    float dw = d[2] * 0.2f, dh = d[3] * 0.2f;
    float pcx = dx * w + cx;
    float pcy = dy * h + cy;
    float pw  = expf(dw) * w;
    float ph  = expf(dh) * h;
    float X1 = fminf(fmaxf(pcx - 0.5f * pw, 0.0f), W - 1.0f);
    float Y1 = fminf(fmaxf(pcy - 0.5f * ph, 0.0f), H - 1.0f);
    float X2 = fminf(fmaxf(pcx + 0.5f * pw, 0.0f), W - 1.0f);
    float Y2 = fminf(fmaxf(pcy + 0.5f * ph, 0.0f), H - 1.0f);
    out[0] = X1 / scale;
    out[1] = Y1 / scale;
    out[2] = X2 / scale;
    out[3] = Y2 / scale;
}

// Per-lane suppression test vs a (wave-uniform) keeper box.
// Arithmetic identical to the absmax-0.0 keep loop -- do not reorder.
__device__ __forceinline__ bool sup_by(
    const float4 kb, float cx1, float cy1, float cx2, float cy2, float car)
{
    const float kar = (kb.z - kb.x + 1.0f) * (kb.w - kb.y + 1.0f);
    const float ix1 = fmaxf(kb.x, cx1), iy1 = fmaxf(kb.y, cy1);
    const float ix2 = fminf(kb.z, cx2), iy2 = fminf(kb.w, cy2);
    const float iw = fmaxf(ix2 - ix1 + 1.0f, 0.0f);
    const float ih = fmaxf(iy2 - iy1 + 1.0f, 0.0f);
    const float inter = iw * ih;
    return inter / (kar + car - inter) > NMS_T;
}

// Register bitonic sort, descending, over SN elements laid out as
// index i = s*64 + lane (slot-major), on ONE wave.  Keys are u64
// (score<<32|~slot) reinterpreted as POSITIVE doubles (exponent normal,
// never NaN), so f64 fmax/fmin ordering == u64 ordering.
template<int SN>
__device__ __forceinline__ void bitonic_desc(double* kd, int lane)
{
    constexpr int NS = SN / 64;
    #pragma unroll
    for (int k = 2; k <= SN; k <<= 1) {
        #pragma unroll
        for (int j = k >> 1; j >= 1; j >>= 1) {
            if (j >= 64) {
                const int js = j >> 6;
                #pragma unroll
                for (int s = 0; s < NS; ++s) {
                    if ((s & js) == 0) {
                        const int sp = s | js;
                        const bool d = (((s << 6) & k) == 0);  // compile-time
                        const double a = kd[s], bb = kd[sp];
                        kd[s]  = d ? fmax(a, bb) : fmin(a, bb);
                        kd[sp] = d ? fmin(a, bb) : fmax(a, bb);
                    }
                }
            } else {
                #pragma unroll
                for (int s = 0; s < NS; ++s) {
                    const double o = __shfl_xor(kd[s], j);
                    const bool lower = (lane & j) == 0;
                    const bool d = ((((s << 6) | lane) & k) == 0);
                    const bool takeMax = (d == lower);
                    const double mx = fmax(kd[s], o);
                    const double mn = fmin(kd[s], o);
                    kd[s] = takeMax ? mx : mn;
                }
            }
        }
    }
}

// Kernel 1: one 4-wave block per (stream, image, class).
// Pipelined collect -> shfl prefix scan -> gather -> [wave 0: register
// bitonic sort || waves 1-3: decode by slot] -> permute to sorted order ->
// wave-0 sorted-scan NMS with 4-WIDE SPECULATIVE keep loop.
__global__ __launch_bounds__(BNTH, 1) void nms_kernel(
    const float* __restrict__ rois_A, const float* __restrict__ cls_A,
    const float* __restrict__ pred_A, const float* __restrict__ info_A,
    const float* __restrict__ rois_B, const float* __restrict__ cls_B,
    const float* __restrict__ pred_B, const float* __restrict__ info_B,
    int Bimg, int N, int C,
    float* __restrict__ kept_scores, int* __restrict__ kcounts,
    float* __restrict__ cls_box, int* __restrict__ sync_counter)
{
    const int FG = C - 1;
    const int bx = blockIdx.x;
    const int st  = bx / (Bimg * FG);
    const int rem = bx % (Bimg * FG);
    const int b = rem / FG;
    const int j = rem % FG;
    const int c = j + 1;
    const int tid = threadIdx.x;
    const int w = tid >> 6;
    const int lane = tid & 63;
    const int SEGW = (N + 63) >> 6;              // <= SEGW_MAX

    if (bx == 0 && tid == 0) *sync_counter = 0;  // ordered before kernel 2

    const float* rois = st ? rois_B : rois_A;
    const float* cls  = st ? cls_B  : cls_A;
    const float* pred = st ? pred_B : pred_A;
    const float* info = st ? info_B : info_A;

    __shared__ uint64_t segKeys[SEGW_MAX][64];   // 16 KB; reused as boxS later
    __shared__ int segCnt[SEGW_MAX];
    __shared__ int offL[SEGW_MAX + 1];
    __shared__ uint64_t keysL[CAP];
    __shared__ unsigned short rowsL[CAP];
    __shared__ float4 boxL[CAP];                 // slot-indexed boxes
    __shared__ float4 keptL[MAXK];

    float4* boxS = (float4*)segKeys;             // sorted-order boxes (16 KB)

    // ---- Collect, PIPELINED: all 8 strided loads issued before ballots ----
    float scv[RMAX];
    #pragma unroll
    for (int r = 0; r < RMAX; ++r) {
        const int seg = w + 4 * r;
        const int n = seg * 64 + lane;
        scv[r] = 0.0f;
        if (seg < SEGW && n < N)
            scv[r] = cls[((size_t)b * N + n) * C + c];
    }
    #pragma unroll
    for (int r = 0; r < RMAX; ++r) {
        const int seg = w + 4 * r;
        if (seg < SEGW) {
            const int n = seg * 64 + lane;
            const bool val = scv[r] > THRESH_F;
            const uint64_t bal = __ballot(val);
            if (val) {
                const int slot = __popcll(bal & ((1ull << lane) - 1ull));
                segKeys[seg][slot] =
                    ((uint64_t)__float_as_uint(scv[r]) << 32) |
                    (uint32_t)(~(uint32_t)n);
            }
            if (lane == 0) segCnt[seg] = __popcll(bal);
        }
    }
    __syncthreads();

    // ---- Segment counts -> exclusive offsets (wave-0 shfl scan) ----
    if (tid < 64) {
        int v = (lane < SEGW) ? segCnt[lane] : 0;
        #pragma unroll
        for (int d = 1; d < 64; d <<= 1) {
            const int o = __shfl_up(v, d);
            if (lane >= d) v += o;
        }
        if (lane < SEGW) offL[lane + 1] = v;
        if (lane == 0) offL[0] = 0;
    }
    __syncthreads();
    const int Mfull = offL[SEGW];
    const int M = Mfull < CAP ? Mfull : CAP;

    // ---- Gather: keysL[i] = (score<<32)|~i, rowsL[i] = row.  Slot order ==
    // row order, so ~slot tie-breaking == reference ~row tie-breaking. ----
    for (int i = tid; i < CAP; i += BNTH) {
        uint64_t k = 0ull;
        if (i < M) {
            int lo = 0, hi = SEGW;
            while (hi - lo > 1) {
                const int mid = (lo + hi) >> 1;
                if (offL[mid] <= i) lo = mid; else hi = mid;
            }
            const uint64_t u = segKeys[lo][i - offL[lo]];
            rowsL[i] = (unsigned short)(~(uint32_t)u);
            k = (u & 0xFFFFFFFF00000000ull) | (uint32_t)(~(uint32_t)i);
        }
        keysL[i] = k;
    }
    __syncthreads();

    const float H = info[b * 3 + 0];
    const float W = info[b * 3 + 1];
    const float scale = info[b * 3 + 2];

    // ---- OVERLAPPED: wave 0 sorts keys (registers) while waves 1-3 decode
    // all M boxes into boxL[slot] (slot-indexed; independent of the sort) ----
    if (tid < 64) {
        if (M > 1) {
            if (M <= 512) {
                double kd[8];
                #pragma unroll
                for (int s = 0; s < 8; ++s)
                    kd[s] = __longlong_as_double((long long)keysL[s * 64 + lane]);
                bitonic_desc<512>(kd, lane);
                #pragma unroll
                for (int s = 0; s < 8; ++s)
                    keysL[s * 64 + lane] = (uint64_t)__double_as_longlong(kd[s]);
            } else {
                double kd[16];
                #pragma unroll
                for (int s = 0; s < 16; ++s)
                    kd[s] = __longlong_as_double((long long)keysL[s * 64 + lane]);
                bitonic_desc<1024>(kd, lane);
                #pragma unroll
                for (int s = 0; s < 16; ++s)
                    keysL[s * 64 + lane] = (uint64_t)__double_as_longlong(kd[s]);
            }
        }
    } else {
        for (int i = tid - 64; i < M; i += BNTH - 64) {
            const int n = rowsL[i];
            float o[4];
            decode_box(rois, pred, H, W, scale, b, n, c, N, C, o);
            boxL[i] = make_float4(o[0], o[1], o[2], o[3]);
        }
    }
    __syncthreads();

    // ---- Permute boxes into sorted order (all waves, one LDS pass) ----
    for (int i = tid; i < M; i += BNTH) {
        const int slot = (int)(~(uint32_t)keysL[i]) & (CAP - 1);
        boxS[i] = boxL[slot];
    }
    __syncthreads();

    // ---- Scan NMS over sorted order on wave 0, 64 candidates per batch ----
    if (tid < 64) {
        float* ksc = kept_scores + (size_t)bx * MAXK;
        int kcount = 0;
        float4 cls_best = make_float4(0.f, 0.f, 0.f, 0.f);

        for (int s = 0; s * 64 < M && kcount < MAXK; ++s) {
            const int ii = s * 64 + lane;
            const bool valid = (ii < M);
            float cx1 = 0.f, cy1 = 0.f, cx2 = 0.f, cy2 = 0.f, car = 1.0f, csc = 0.f;
            if (valid) {
                const float4 cb4 = boxS[ii];
                cx1 = cb4.x; cy1 = cb4.y; cx2 = cb4.z; cy2 = cb4.w;
                car = (cx2 - cx1 + 1.0f) * (cy2 - cy1 + 1.0f);
                csc = __uint_as_float((uint32_t)(keysL[ii] >> 32));
            }
            // Pre-suppression vs already-kept boxes (uniform loop, pipelined).
            bool sup = !valid;
            for (int q = 0; q < kcount; ++q) {
                const float4 kb = keptL[q];
                sup = sup || sup_by(kb, cx1, cy1, cx2, cy2, car);
            }
            uint64_t alive = ~__ballot(sup);

            // 4-WIDE SPECULATIVE keep loop: commit l1 always; l2/l3/l4 iff
            // not suppressed by an earlier COMMITTED speculated keeper.
            // Identical decisions to sequential greedy (suppressed spec lanes
            // are removed via the committing keeper's own ballot).
            while (alive != 0ull && kcount < MAXK) {
                const int pa = (int)__popcll(alive);
                int n_spec = pa < 4 ? pa : 4;
                const int room = MAXK - kcount;
                if (n_spec > room) n_spec = room;

                uint64_t a = alive;
                const int l1 = __builtin_ctzll(a); a &= a - 1;
                const int l2 = a ? __builtin_ctzll(a) : 0; a &= a - 1;
                const int l3 = a ? __builtin_ctzll(a) : 0; a &= a - 1;
                const int l4 = a ? __builtin_ctzll(a) : 0;

                const float4 kb1 = boxS[s * 64 + l1];   // uniform broadcasts,
                const float4 kb2 = boxS[s * 64 + l2];   // pipelined (1 latency)
                const float4 kb3 = boxS[s * 64 + l3];
                const float4 kb4 = boxS[s * 64 + l4];

                const uint64_t b1 = __ballot(sup_by(kb1, cx1, cy1, cx2, cy2, car));
                const uint64_t b2 = __ballot(sup_by(kb2, cx1, cy1, cx2, cy2, car));
                const uint64_t b3 = __ballot(sup_by(kb3, cx1, cy1, cx2, cy2, car));
                const uint64_t b4 = __ballot(sup_by(kb4, cx1, cy1, cx2, cy2, car));

                const bool k2 = (n_spec >= 2) && !((b1 >> l2) & 1ull);
                const bool k3 = (n_spec >= 3) && !((b1 >> l3) & 1ull)
                                              && !(k2 && ((b2 >> l3) & 1ull));
                const bool k4 = (n_spec >= 4) && !((b1 >> l4) & 1ull)
                                              && !(k2 && ((b2 >> l4) & 1ull))
                                              && !(k3 && ((b3 >> l4) & 1ull));

                const int p2 = kcount + 1;
                const int p3 = kcount + 1 + (k2 ? 1 : 0);
                const int p4 = kcount + 1 + (k2 ? 1 : 0) + (k3 ? 1 : 0);
                const float4 mybox = make_float4(cx1, cy1, cx2, cy2);
                if (lane == l1)       { keptL[kcount] = mybox; ksc[kcount] = csc; }
                if (k2 && lane == l2) { keptL[p2] = mybox; ksc[p2] = csc; }
                if (k3 && lane == l3) { keptL[p3] = mybox; ksc[p3] = csc; }
                if (k4 && lane == l4) { keptL[p4] = mybox; ksc[p4] = csc; }
                if (kcount == 0) cls_best = kb1;       // first keep overall

                uint64_t remv = b1 | (1ull << l1);
                if (k2) remv |= b2 | (1ull << l2);
                if (k3) remv |= b3 | (1ull << l3);
                if (k4) remv |= b4 | (1ull << l4);
                alive &= ~remv;
                kcount += 1 + (k2 ? 1 : 0) + (k3 ? 1 : 0) + (k4 ? 1 : 0);
            }
        }

        if (lane == 0) {
            kcounts[bx] = kcount;
            float* cbp = cls_box + (size_t)bx * 4;
            cbp[0] = cls_best.x; cbp[1] = cls_best.y;
            cbp[2] = cls_best.z; cbp[3] = cls_best.w;
        }
    }
}

// Kernel 2: one block per (stream, image): global top-50 cap via 6-step
// binary-search count (desc lists -> prefix predicate -> lower bound ==
// exact count), then the LAST finished block does the joint A*B argmax +
// output gather (device-scope atomic gate).
__global__ __launch_bounds__(64) void select_combine(
    const float* __restrict__ kept_scores, const int* __restrict__ kcounts,
    const float* __restrict__ cls_box,
    const float* __restrict__ rois_A, const float* __restrict__ pred_A,
    const float* __restrict__ info_A,
    const float* __restrict__ rois_B, const float* __restrict__ pred_B,
    const float* __restrict__ info_B,
    int Bimg, int N, int C,
    float* best_s, float* best_b, int* sync_counter, float* __restrict__ out)
{
    const int FG = C - 1;
    const int bx = blockIdx.x;           // st*Bimg + b
    const int st = bx / Bimg;
    const int b  = bx % Bimg;
    const int tid = threadIdx.x;

    __shared__ float sk[20][MAXK];
    __shared__ int   skc[20];
    __shared__ float stopv[20];
    __shared__ int   cnt20[20];
    __shared__ int   inflag[20];
    __shared__ float gbox[4];
    __shared__ int   amlast;

    const size_t base = (size_t)bx * FG;
    for (int i = tid; i < FG * MAXK; i += 64)
        sk[i / MAXK][i % MAXK] = kept_scores[base * MAXK + i];
    if (tid < FG) {
        skc[tid] = kcounts[base + tid];
        cnt20[tid] = 0;
    }
    __syncthreads();
    if (tid < FG)
        stopv[tid] = (skc[tid] > 0) ? sk[tid][0] : -INFINITY;
    __syncthreads();

    // Count entries strictly greater than each class's best: 400 pairs over
    // 64 lanes, 6-step binary search per pair.
    for (int p = tid; p < FG * FG; p += 64) {
        const int cc = p / FG;     // candidate class
        const int c2 = p % FG;     // donor class
        const float sc = stopv[cc];
        const int k2 = skc[c2];
        int cnt = 0;
        if (skc[cc] > 0 && k2 > 0) {
            const float* lp = &sk[c2][0];
            int lo = 0, hi = k2;
            while (lo < hi) {
                const int mid = (lo + hi) >> 1;
                const float v = lp[mid];
                const bool greater = (v > sc) || (v == sc && c2 < cc);
                if (greater) lo = mid + 1; else hi = mid;
            }
            cnt = lo;
        }
        if (cnt) atomicAdd(&cnt20[cc], cnt);
    }
    __syncthreads();
    if (tid < FG)
        inflag[tid] = (skc[tid] > 0 && cnt20[tid] < MAXK) ? 1 : 0;
    __syncthreads();

    if (tid == 0) {
        int g = -1;
        float bs = -INFINITY;
        for (int c2 = 0; c2 < FG; ++c2)
            if (skc[c2] > 0 && stopv[c2] > bs) { bs = stopv[c2]; g = c2; }
        if (g >= 0) {
            const float* cbp = cls_box + (base + g) * 4;
            gbox[0] = cbp[0]; gbox[1] = cbp[1]; gbox[2] = cbp[2]; gbox[3] = cbp[3];
        } else {
            const float* rois = st ? rois_B : rois_A;
            const float* pred = st ? pred_B : pred_A;
            const float* info = st ? info_B : info_A;
            float o[4];
            decode_box(rois, pred, info[b * 3], info[b * 3 + 1], info[b * 3 + 2],
                       b, 0, 1, N, C, o);
            gbox[0] = o[0]; gbox[1] = o[1]; gbox[2] = o[2]; gbox[3] = o[3];
        }
    }
    __syncthreads();

    if (tid < FG) {
        const int in = inflag[tid];
        best_s[base + tid] = in ? stopv[tid] : -INFINITY;
        float* ob = best_b + (base + tid) * 4;
        if (in) {
            const float* cbp = cls_box + (base + tid) * 4;
            ob[0] = cbp[0]; ob[1] = cbp[1]; ob[2] = cbp[2]; ob[3] = cbp[3];
        } else {
            ob[0] = gbox[0]; ob[1] = gbox[1]; ob[2] = gbox[2]; ob[3] = gbox[3];
        }
    }

    // ---- last-done block performs the combine ----
    __threadfence();
    if (tid == 0) amlast = (atomicAdd(sync_counter, 1) == 2 * Bimg - 1);
    __syncthreads();
    if (amlast) {
        __threadfence();   // acquire: other blocks' best_s/best_b now visible
        if (tid < Bimg) {
            const int i = tid;
            const float* sA = best_s + (size_t)i * FG;
            const float* sB = best_s + (size_t)(Bimg + i) * FG;
            float bj = 0.0f;
            int cls = 0;
            for (int cc = 0; cc < FG; ++cc) {
                const float v = sA[cc] * sB[cc];   // IEEE: -inf*-inf=+inf
                if (cc == 0 || v > bj) { bj = v; cls = cc; }
            }
            const float* bA = best_b + ((size_t)i * FG + cls) * 4;
            const float* bB = best_b + ((size_t)(Bimg + i) * FG + cls) * 4;
            for (int k = 0; k < 4; ++k) {
                out[i * 4 + k]            = bA[k];
                out[Bimg * 4 + i * 4 + k] = bB[k];
            }
        }
    }
}

extern "C" void kernel_launch(void* const* d_in, const int* in_sizes, int n_in,
                              void* d_out, int out_size, void* d_ws, size_t ws_size,
                              hipStream_t stream) {
    const float* rois_A = (const float*)d_in[0];
    const float* cls_A  = (const float*)d_in[1];
    const float* pred_A = (const float*)d_in[2];
    const float* info_A = (const float*)d_in[3];
    const float* rois_B = (const float*)d_in[4];
    const float* cls_B  = (const float*)d_in[5];
    const float* pred_B = (const float*)d_in[6];
    const float* info_B = (const float*)d_in[7];
    float* out = (float*)d_out;

    const int Bimg = in_sizes[3] / 3;                  // 8
    const int N    = in_sizes[0] / (Bimg * 5);         // 2000
    const int C    = in_sizes[1] / (Bimg * N);         // 21
    const int FG   = C - 1;                            // 20
    const int NSB  = 2 * Bimg * FG;                    // 320 tasks

    // Workspace (everything overwritten each call; no resets needed).
    char* ws = (char*)d_ws;
    int* sync_counter = (int*)ws;
    size_t off = 256;
    float* kept_scores = (float*)(ws + off);               // [320][50]
    off += (size_t)NSB * MAXK * sizeof(float);
    int* kcounts = (int*)(ws + off);                       // [320]
    off += (size_t)NSB * sizeof(int);
    float* cls_box = (float*)(ws + off);                   // [320][4]
    off += (size_t)NSB * 4 * sizeof(float);
    float* best_s = (float*)(ws + off);                    // [320]
    off += (size_t)NSB * sizeof(float);
    float* best_b = (float*)(ws + off);                    // [320][4]

    nms_kernel<<<NSB, BNTH, 0, stream>>>(
        rois_A, cls_A, pred_A, info_A,
        rois_B, cls_B, pred_B, info_B,
        Bimg, N, C, kept_scores, kcounts, cls_box, sync_counter);

    select_combine<<<2 * Bimg, 64, 0, stream>>>(
        kept_scores, kcounts, cls_box,
        rois_A, pred_A, info_A, rois_B, pred_B, info_B,
        Bimg, N, C, best_s, best_b, sync_counter, out);
}